// Round 2
// baseline (736.907 us; speedup 1.0000x reference)
//
#include <hip/hip_runtime.h>
#include <hip/hip_cooperative_groups.h>
#include <cstddef>

namespace cg = cooperative_groups;

// Problem constants (from reference)
#define QN 10000
#define DD 64
#define MM 50
#define BB 64
#define TT 512
#define WPAD 52   // padded w row stride in floats (208 B -> 16B-aligned rows)
#define MG 25     // m's per wave in the 2-way m-split scan phases

// ===========================================================================
// Device phase helpers — shared by the fused cooperative kernel and the
// discrete-kernel fallback. All phases are grid-stride over their unit space
// so they are correct for ANY grid size.
// ===========================================================================

// ---- Phase 0: w = softmax(k@Mk^T); e = sigmoid(v@e_W+e_b)*mask;
//      a = tanh(v@a_W+a_b)*mask. Waves split into 3 roles so no role needs
//      more than ~64 weight VGPRs (keeps fused kernel under 128 VGPR).
__device__ __forceinline__ void phase0(
    int gw, int NWv, int lane,
    const int* __restrict__ question, const int* __restrict__ response,
    const float* __restrict__ mask,
    const float* __restrict__ k_emb, const float* __restrict__ v_emb,
    const float* __restrict__ Mk,
    const float* __restrict__ e_W, const float* __restrict__ e_b,
    const float* __restrict__ a_W, const float* __restrict__ a_b,
    float* __restrict__ w_buf, float* __restrict__ e_buf,
    float* __restrict__ a_buf) {
  const int third = NWv / 3;
  if (gw < third) {                       // role: w (softmax)
    float mk[64];
    const int mrow = lane < MM ? lane : (MM - 1);
#pragma unroll
    for (int i = 0; i < 64; i += 4) {
      const float4 t4 = *(const float4*)(Mk + mrow * 64 + i);
      mk[i] = t4.x; mk[i + 1] = t4.y; mk[i + 2] = t4.z; mk[i + 3] = t4.w;
    }
    for (int row = gw; row < BB * TT; row += third) {
      const int q = question[row];                     // wave-uniform
      const float* __restrict__ krow = k_emb + (size_t)q * 64;
      float l0 = 0.f, l1 = 0.f, l2 = 0.f, l3 = 0.f;
#pragma unroll
      for (int i = 0; i < 64; i += 4) {
        const float4 kv = *(const float4*)(krow + i);  // uniform -> s_load
        l0 = fmaf(kv.x, mk[i], l0);
        l1 = fmaf(kv.y, mk[i + 1], l1);
        l2 = fmaf(kv.z, mk[i + 2], l2);
        l3 = fmaf(kv.w, mk[i + 3], l3);
      }
      const float lm = (l0 + l1) + (l2 + l3);
      float lv = (lane < MM) ? lm : -3.4e38f;
#pragma unroll
      for (int off = 32; off > 0; off >>= 1) lv = fmaxf(lv, __shfl_xor(lv, off));
      float pe = (lane < MM) ? __expf(lm - lv) : 0.f;
      float ss = pe;
#pragma unroll
      for (int off = 32; off > 0; off >>= 1) ss += __shfl_xor(ss, off);
      if (lane < MM) w_buf[(size_t)row * WPAD + lane] = pe / ss;
    }
  } else if (gw < 2 * third) {            // role: e
    float ew[64];
#pragma unroll
    for (int i = 0; i < 64; ++i) ew[i] = e_W[i * 64 + lane];
    const float eb = e_b[lane];
    for (int row = gw - third; row < BB * TT; row += third) {
      const int q = question[row];
      const int r = response[row];
      const float mf = (mask[row] == 1.0f) ? 1.0f : 0.0f;
      const float* __restrict__ vrow = v_emb + ((size_t)q + (size_t)QN * r) * 64;
      float e0 = eb, e1 = 0.f;
#pragma unroll
      for (int i = 0; i < 64; i += 2) {
        const float2 vv = *(const float2*)(vrow + i);  // uniform -> s_load
        e0 = fmaf(vv.x, ew[i], e0);
        e1 = fmaf(vv.y, ew[i + 1], e1);
      }
      const float se = e0 + e1;
      e_buf[(size_t)row * 64 + lane] = mf / (1.f + __expf(-se));
    }
  } else {                                // role: a
    const int stride = NWv - 2 * third;
    float aw[64];
#pragma unroll
    for (int i = 0; i < 64; ++i) aw[i] = a_W[i * 64 + lane];
    const float ab = a_b[lane];
    for (int row = gw - 2 * third; row < BB * TT; row += stride) {
      const int q = question[row];
      const int r = response[row];
      const float mf = (mask[row] == 1.0f) ? 1.0f : 0.0f;
      const float* __restrict__ vrow = v_emb + ((size_t)q + (size_t)QN * r) * 64;
      float a0 = ab, a1 = 0.f;
#pragma unroll
      for (int i = 0; i < 64; i += 2) {
        const float2 vv = *(const float2*)(vrow + i);
        a0 = fmaf(vv.x, aw[i], a0);
        a1 = fmaf(vv.y, aw[i + 1], a1);
      }
      const float sa = a0 + a1;
      const float t2 = __expf(2.f * sa);
      a_buf[(size_t)row * 64 + lane] = mf * (1.f - 2.f / (t2 + 1.f));
    }
  }
}

// ---- Phase A: per-(b,chunk,mgroup) composed affine (A,B) per (m,d).
//      Branchless (mask folded into e/a in phase 0).
__device__ __forceinline__ void phaseA(
    int gw, int NWv, int lane, int logC, int L,
    const float* __restrict__ w_buf, const float* __restrict__ e_buf,
    const float* __restrict__ a_buf, float* __restrict__ AB) {
  const int C = 1 << logC;
  for (int u2 = gw; u2 < BB * C * 2; u2 += NWv) {
    const int g = u2 & 1;
    const int unit = u2 >> 1;                          // b*C + c
    const int b = unit >> logC;
    const int c = unit & (C - 1);
    float Am[MG], Bm[MG];
#pragma unroll
    for (int m = 0; m < MG; ++m) { Am[m] = 1.f; Bm[m] = 0.f; }
    const size_t rowbase = (size_t)b * TT + c * L;
#pragma unroll 2
    for (int j = 0; j < L; ++j) {
      const size_t row = rowbase + j;
      const float ed = e_buf[row * 64 + lane];
      const float ad = a_buf[row * 64 + lane];
      const float* __restrict__ wr = w_buf + row * WPAD + g * MG; // uniform
#pragma unroll
      for (int m = 0; m < MG; ++m) {
        const float wm = wr[m];
        const float al = fmaf(-wm, ed, 1.0f);
        const float be = wm * ad;
        Am[m] *= al;
        Bm[m] = fmaf(Bm[m], al, be);
      }
    }
    float* __restrict__ abp = AB + (size_t)unit * 6400 + (g * MG) * 128 + lane * 2;
#pragma unroll
    for (int m = 0; m < MG; ++m) {
      float2 o; o.x = Am[m]; o.y = Bm[m];
      *(float2*)(abp + m * 128) = o;
    }
  }
}

// ---- Phase B: sequential over C chunks, parallel over B*M*D elements.
__device__ __forceinline__ void phaseB(
    int tid, int NT, const float* __restrict__ AB,
    const float* __restrict__ Mv0, float* __restrict__ entry, int C) {
  for (int idx = tid; idx < BB * MM * 64; idx += NT) {
    const int b = idx / (MM * 64);
    const int r = idx - b * (MM * 64);                 // m*64 + d
    float s = Mv0[r];
    const float* __restrict__ abp = AB + (size_t)b * C * 6400 + (size_t)r * 2;
    float* __restrict__ ep = entry + (size_t)b * C * 3200 + r;
    if (C == 32) {
      float2 ab[32];
#pragma unroll
      for (int c = 0; c < 32; ++c)
        ab[c] = *(const float2*)(abp + (size_t)c * 6400);
#pragma unroll
      for (int c = 0; c < 32; ++c) {
        ep[(size_t)c * 3200] = s;
        s = fmaf(ab[c].x, s, ab[c].y);
      }
    } else {
      float2 cur = *(const float2*)(abp);
      for (int c = 0; c < C; ++c) {
        ep[(size_t)c * 3200] = s;
        float2 nxt; nxt.x = 1.f; nxt.y = 0.f;
        if (c + 1 < C) nxt = *(const float2*)(abp + (size_t)(c + 1) * 6400);
        s = fmaf(cur.x, s, cur.y);
        cur = nxt;
      }
    }
  }
}

// ---- Phase C: replay each chunk from its entry state, emitting partial reads.
__device__ __forceinline__ void phaseC(
    int gw, int NWv, int lane, int logC, int L, int useChunks,
    const float* __restrict__ w_buf, const float* __restrict__ e_buf,
    const float* __restrict__ a_buf, const float* __restrict__ entry,
    const float* __restrict__ Mv0, float* __restrict__ read2) {
  const int C = 1 << logC;
  const size_t RN = (size_t)BB * (TT - 1) * 64;
  for (int u2 = gw; u2 < BB * C * 2; u2 += NWv) {
    const int g = u2 & 1;
    const int unit = u2 >> 1;                          // b*C + c
    const int b = unit >> logC;
    const int c = unit & (C - 1);
    float s[MG];
    if (!useChunks) {
#pragma unroll
      for (int m = 0; m < MG; ++m) s[m] = Mv0[(g * MG + m) * 64 + lane];
    } else {
      const float* __restrict__ ep =
          entry + (size_t)unit * 3200 + (g * MG) * 64 + lane;
#pragma unroll
      for (int m = 0; m < MG; ++m) s[m] = ep[m * 64];
    }
    const int t0 = c * L;
    float* __restrict__ rb = read2 + (size_t)g * RN;
    int j0 = 0;
    if (t0 == 0) {
      // step t=0: update only, no read emitted
      const size_t row = (size_t)b * TT;
      const float ed = e_buf[row * 64 + lane];
      const float ad = a_buf[row * 64 + lane];
      const float* __restrict__ wr = w_buf + row * WPAD + g * MG;
#pragma unroll
      for (int m = 0; m < MG; ++m)
        s[m] = fmaf(wr[m], fmaf(-s[m], ed, ad), s[m]);
      j0 = 1;
    }
#pragma unroll 2
    for (int j = j0; j < L; ++j) {
      const int t = t0 + j;
      const size_t row = (size_t)b * TT + t;
      const float ed = e_buf[row * 64 + lane];
      const float ad = a_buf[row * 64 + lane];
      const float* __restrict__ wr = w_buf + row * WPAD + g * MG; // uniform
      float a0 = 0.f, a1 = 0.f;
#pragma unroll
      for (int m = 0; m < MG - 1; m += 2) {
        a0 = fmaf(wr[m], s[m], a0);
        a1 = fmaf(wr[m + 1], s[m + 1], a1);
      }
      a0 = fmaf(wr[MG - 1], s[MG - 1], a0);            // MG=25 is odd
      rb[((size_t)b * (TT - 1) + (t - 1)) * 64 + lane] = a0 + a1;
#pragma unroll
      for (int m = 0; m < MG; ++m)
        s[m] = fmaf(wr[m], fmaf(-s[m], ed, ad), s[m]);
    }
  }
}

// ---- Phase D: f = tanh([read | k_{t+1}] @ f_W + f_b); p = f @ p_W + p_b.
//      f_W split across wave pairs (64 VGPR each); partials exchanged in LDS.
//      Wave pairing: u parity == wslot parity (NWv multiple of 4), so waves
//      (wslot 0,1) and (2,3) in a block always share a row.
__device__ __forceinline__ void phaseD(
    int gw, int NWv, int lane, int wslot,
    const int* __restrict__ question, const float* __restrict__ k_emb,
    const float* __restrict__ read2,
    const float* __restrict__ f_W, const float* __restrict__ f_b,
    const float* __restrict__ p_W, const float* __restrict__ p_b,
    float* __restrict__ out) {
  __shared__ float pbuf[2][2][64];                     // [parity][pair][lane]
  const size_t RN = (size_t)BB * (TT - 1) * 64;
  const int UD = BB * (TT - 1) * 2;                    // rows x 2 roles
  const int iters = (UD + NWv - 1) / NWv;              // padded: all waves
  const int g = wslot & 1;
  float fw[64];
#pragma unroll
  for (int i = 0; i < 64; ++i) fw[i] = f_W[(g * 64 + i) * 64 + lane];
  const float fb = f_b[lane];
  const float pw = p_W[lane];
  const float pb = p_b[0];
  for (int it = 0; it < iters; ++it) {
    const int u = gw + it * NWv;
    const bool active = (u < UD);
    const int row = u >> 1;
    float partial = 0.f;
    if (active) {
      if (g == 0) {                                    // read-half of f_W
        const float* __restrict__ r0 = read2 + (size_t)row * 64;
        const float* __restrict__ r1 = r0 + RN;
        float f0 = 0.f, f1 = 0.f, f2 = 0.f, f3 = 0.f;
#pragma unroll
        for (int i = 0; i < 64; i += 4) {
          const float4 x0 = *(const float4*)(r0 + i);  // uniform -> s_load
          const float4 x1 = *(const float4*)(r1 + i);
          f0 = fmaf(x0.x + x1.x, fw[i], f0);
          f1 = fmaf(x0.y + x1.y, fw[i + 1], f1);
          f2 = fmaf(x0.z + x1.z, fw[i + 2], f2);
          f3 = fmaf(x0.w + x1.w, fw[i + 3], f3);
        }
        partial = (f0 + f1) + (f2 + f3);
      } else {                                         // k-half of f_W
        const int b = row / (TT - 1);
        const int tp = row - b * (TT - 1);
        const int qn = question[b * TT + tp + 1];      // wave-uniform
        const float* __restrict__ krow = k_emb + (size_t)qn * 64;
        float f0 = 0.f, f1 = 0.f, f2 = 0.f, f3 = 0.f;
#pragma unroll
        for (int i = 0; i < 64; i += 4) {
          const float4 kv = *(const float4*)(krow + i);
          f0 = fmaf(kv.x, fw[i], f0);
          f1 = fmaf(kv.y, fw[i + 1], f1);
          f2 = fmaf(kv.z, fw[i + 2], f2);
          f3 = fmaf(kv.w, fw[i + 3], f3);
        }
        partial = (f0 + f1) + (f2 + f3);
      }
    }
    const int pr = it & 1;                             // LDS parity dbuf
    if (active && g == 1) pbuf[pr][wslot >> 1][lane] = partial;
    __syncthreads();
    if (active && g == 0) {
      const float fsum = partial + pbuf[pr][wslot >> 1][lane] + fb;
      const float t2 = __expf(2.f * fsum);
      const float fv = 1.f - 2.f / (t2 + 1.f);         // tanh
      float acc = fv * pw;
#pragma unroll
      for (int off = 32; off > 0; off >>= 1) acc += __shfl_xor(acc, off);
      if (lane == 0) out[row] = acc + pb;
    }
  }
}

// ===========================================================================
// Fused cooperative kernel: one dispatch for the whole pipeline.
// __launch_bounds__(256,4): 4 waves/EU -> VGPR<=128 -> 4 blocks/CU, so a
// 1024-block grid is co-resident for grid.sync().
// ===========================================================================
__global__ __launch_bounds__(256, 4) void kFused(
    const int* __restrict__ question, const int* __restrict__ response,
    const float* __restrict__ mask,
    const float* __restrict__ k_emb, const float* __restrict__ v_emb,
    const float* __restrict__ Mk, const float* __restrict__ Mv0,
    const float* __restrict__ e_W, const float* __restrict__ e_b,
    const float* __restrict__ a_W, const float* __restrict__ a_b,
    const float* __restrict__ f_W, const float* __restrict__ f_b,
    const float* __restrict__ p_W, const float* __restrict__ p_b,
    float* __restrict__ out,
    float* __restrict__ w_buf, float* __restrict__ e_buf,
    float* __restrict__ a_buf, float* __restrict__ read2,
    float* __restrict__ AB, float* __restrict__ entry,
    int logC, int L, int useChunks) {
  cg::grid_group grid = cg::this_grid();
  const int lane = (int)(threadIdx.x & 63);
  const int wslot = __builtin_amdgcn_readfirstlane((int)(threadIdx.x >> 6));
  const int gw = blockIdx.x * 4 + wslot;
  const int NWv = gridDim.x * 4;

  phase0(gw, NWv, lane, question, response, mask, k_emb, v_emb, Mk,
         e_W, e_b, a_W, a_b, w_buf, e_buf, a_buf);
  __threadfence();
  grid.sync();

  if (useChunks) {                                     // grid-uniform branch
    phaseA(gw, NWv, lane, logC, L, w_buf, e_buf, a_buf, AB);
    __threadfence();
    grid.sync();
    phaseB(blockIdx.x * 256 + (int)threadIdx.x, gridDim.x * 256,
           AB, Mv0, entry, 1 << logC);
    __threadfence();
    grid.sync();
  }

  phaseC(gw, NWv, lane, logC, L, useChunks, w_buf, e_buf, a_buf,
         entry, Mv0, read2);
  __threadfence();
  grid.sync();

  phaseD(gw, NWv, lane, wslot, question, k_emb, read2,
         f_W, f_b, p_W, p_b, out);
}

// ===========================================================================
// Discrete-kernel fallback (used only if cooperative launch fails).
// ===========================================================================
__global__ __launch_bounds__(256) void kP0(
    const int* __restrict__ question, const int* __restrict__ response,
    const float* __restrict__ mask,
    const float* __restrict__ k_emb, const float* __restrict__ v_emb,
    const float* __restrict__ Mk,
    const float* __restrict__ e_W, const float* __restrict__ e_b,
    const float* __restrict__ a_W, const float* __restrict__ a_b,
    float* __restrict__ w_buf, float* __restrict__ e_buf,
    float* __restrict__ a_buf) {
  const int lane = (int)(threadIdx.x & 63);
  const int wslot = __builtin_amdgcn_readfirstlane((int)(threadIdx.x >> 6));
  phase0(blockIdx.x * 4 + wslot, gridDim.x * 4, lane, question, response, mask,
         k_emb, v_emb, Mk, e_W, e_b, a_W, a_b, w_buf, e_buf, a_buf);
}

__global__ __launch_bounds__(256) void kPA(
    const float* __restrict__ w_buf, const float* __restrict__ e_buf,
    const float* __restrict__ a_buf, float* __restrict__ AB, int logC, int L) {
  const int lane = (int)(threadIdx.x & 63);
  const int wslot = __builtin_amdgcn_readfirstlane((int)(threadIdx.x >> 6));
  phaseA(blockIdx.x * 4 + wslot, gridDim.x * 4, lane, logC, L,
         w_buf, e_buf, a_buf, AB);
}

__global__ __launch_bounds__(256) void kPB(
    const float* __restrict__ AB, const float* __restrict__ Mv0,
    float* __restrict__ entry, int C) {
  phaseB(blockIdx.x * 256 + (int)threadIdx.x, gridDim.x * 256,
         AB, Mv0, entry, C);
}

__global__ __launch_bounds__(256) void kPC(
    const float* __restrict__ w_buf, const float* __restrict__ e_buf,
    const float* __restrict__ a_buf, const float* __restrict__ entry,
    const float* __restrict__ Mv0, float* __restrict__ read2,
    int logC, int L, int useChunks) {
  const int lane = (int)(threadIdx.x & 63);
  const int wslot = __builtin_amdgcn_readfirstlane((int)(threadIdx.x >> 6));
  phaseC(blockIdx.x * 4 + wslot, gridDim.x * 4, lane, logC, L, useChunks,
         w_buf, e_buf, a_buf, entry, Mv0, read2);
}

__global__ __launch_bounds__(256) void kPD(
    const int* __restrict__ question, const float* __restrict__ k_emb,
    const float* __restrict__ read2,
    const float* __restrict__ f_W, const float* __restrict__ f_b,
    const float* __restrict__ p_W, const float* __restrict__ p_b,
    float* __restrict__ out) {
  const int lane = (int)(threadIdx.x & 63);
  const int wslot = __builtin_amdgcn_readfirstlane((int)(threadIdx.x >> 6));
  phaseD(blockIdx.x * 4 + wslot, gridDim.x * 4, lane, wslot,
         question, k_emb, read2, f_W, f_b, p_W, p_b, out);
}

// ---------------------------------------------------------------------------
extern "C" void kernel_launch(void* const* d_in, const int* in_sizes, int n_in,
                              void* d_out, int out_size, void* d_ws, size_t ws_size,
                              hipStream_t stream) {
  const int*   question = (const int*)d_in[0];
  const int*   response = (const int*)d_in[1];
  const float* mask     = (const float*)d_in[2];
  const float* k_emb    = (const float*)d_in[3];
  const float* v_emb    = (const float*)d_in[4];
  const float* Mk       = (const float*)d_in[5];
  const float* Mv0      = (const float*)d_in[6];
  const float* e_W      = (const float*)d_in[7];
  const float* e_b      = (const float*)d_in[8];
  const float* a_W      = (const float*)d_in[9];
  const float* a_b      = (const float*)d_in[10];
  const float* f_W      = (const float*)d_in[11];
  const float* f_b      = (const float*)d_in[12];
  const float* p_W      = (const float*)d_in[13];
  const float* p_b      = (const float*)d_in[14];
  float* out = (float*)d_out;

  // workspace layout (floats): planar e/a for fully-coalesced role stores
  const size_t wN  = (size_t)BB * TT * WPAD;       // 1,703,936
  const size_t eN  = (size_t)BB * TT * 64;         // 2,097,152
  const size_t r2N = 2ull * BB * (TT - 1) * 64;    // 4,186,112
  float* ws = (float*)d_ws;
  float* w_buf  = ws;
  float* e_buf  = w_buf + wN;
  float* a_buf  = e_buf + eN;
  float* read2  = a_buf + eN;
  float* AB_arr = read2 + r2N;
  const size_t baseN = wN + 2 * eN + r2N;

  // choose the largest chunk count C that fits the workspace
  // per-C cost: AB (6400*B*C) + entry (3200*B*C) floats
  int C = 32, logC = 5;
  while (C >= 2) {
    const size_t need = (baseN + 9600ull * BB * C) * sizeof(float);
    if (need <= ws_size) break;
    C >>= 1; logC -= 1;
  }
  int useChunks = (C >= 2);
  if (!useChunks) { C = 1; logC = 0; }
  int L = TT / C;
  float* entry = AB_arr + 6400ull * BB * C;

  // grid size for cooperative co-residency (one-time host-only query)
  static int g_nb = 0;
  if (g_nb == 0) {
    int occ = 0;
    if (hipOccupancyMaxActiveBlocksPerMultiprocessor(
            &occ, (const void*)kFused, 256, 0) != hipSuccess || occ < 1)
      occ = 1;
    long nb = (long)occ * 256;   // 256 CUs on MI355X (gfx950)
    if (nb > 1024) nb = 1024;
    if (nb < 4) nb = 4;
    g_nb = (int)nb;
  }

  void* args[] = {
    (void*)&question, (void*)&response, (void*)&mask, (void*)&k_emb,
    (void*)&v_emb, (void*)&Mk, (void*)&Mv0, (void*)&e_W, (void*)&e_b,
    (void*)&a_W, (void*)&a_b, (void*)&f_W, (void*)&f_b, (void*)&p_W,
    (void*)&p_b, (void*)&out, (void*)&w_buf, (void*)&e_buf, (void*)&a_buf,
    (void*)&read2, (void*)&AB_arr, (void*)&entry,
    (void*)&logC, (void*)&L, (void*)&useChunks
  };
  hipError_t err = hipLaunchCooperativeKernel(
      (const void*)kFused, dim3(g_nb), dim3(256), args, 0, stream);

  if (err != hipSuccess) {
    // fallback: discrete phase kernels (same device code, normal launches)
    const int ublocks = (BB * C * 2 + 3) / 4;
    hipLaunchKernelGGL(kP0, dim3(1024), dim3(256), 0, stream,
                       question, response, mask, k_emb, v_emb, Mk,
                       e_W, e_b, a_W, a_b, w_buf, e_buf, a_buf);
    if (useChunks) {
      hipLaunchKernelGGL(kPA, dim3(ublocks), dim3(256), 0, stream,
                         w_buf, e_buf, a_buf, AB_arr, logC, L);
      hipLaunchKernelGGL(kPB, dim3((BB * MM * 64 + 255) / 256), dim3(256), 0,
                         stream, AB_arr, Mv0, entry, C);
    }
    hipLaunchKernelGGL(kPC, dim3(ublocks), dim3(256), 0, stream,
                       w_buf, e_buf, a_buf, entry, Mv0, read2,
                       logC, L, useChunks);
    hipLaunchKernelGGL(kPD, dim3(1024), dim3(256), 0, stream,
                       question, k_emb, read2, f_W, f_b, p_W, p_b, out);
  }
}

// Round 3
// 631.358 us; speedup vs baseline: 1.1672x; 1.1672x over previous
//
#include <hip/hip_runtime.h>
#include <hip/hip_cooperative_groups.h>
#include <cstddef>

namespace cg = cooperative_groups;

// Problem constants (from reference)
#define QN 10000
#define DD 64
#define MM 50
#define BB 64
#define TT 512
#define WPAD 52   // padded w row stride in floats (208 B -> 16B-aligned rows)
#define MG 25     // m's per wave in the 2-way m-split scan phases

// ===========================================================================
// Device phase helpers — shared by the fused cooperative kernel and the
// discrete-kernel fallback. All phases are grid-stride over their unit space
// so they are correct for ANY grid size.
// ===========================================================================

// ---- Phase 0: w = softmax(k@Mk^T); e = sigmoid(v@e_W+e_b)*mask;
//      a = tanh(v@a_W+a_b)*mask. Waves split into 3 roles.
__device__ __forceinline__ void phase0(
    int gw, int NWv, int lane,
    const int* __restrict__ question, const int* __restrict__ response,
    const float* __restrict__ mask,
    const float* __restrict__ k_emb, const float* __restrict__ v_emb,
    const float* __restrict__ Mk,
    const float* __restrict__ e_W, const float* __restrict__ e_b,
    const float* __restrict__ a_W, const float* __restrict__ a_b,
    float* __restrict__ w_buf, float* __restrict__ e_buf,
    float* __restrict__ a_buf) {
  const int third = NWv / 3;
  if (gw < third) {                       // role: w (softmax)
    float mk[64];
    const int mrow = lane < MM ? lane : (MM - 1);
#pragma unroll
    for (int i = 0; i < 64; i += 4) {
      const float4 t4 = *(const float4*)(Mk + mrow * 64 + i);
      mk[i] = t4.x; mk[i + 1] = t4.y; mk[i + 2] = t4.z; mk[i + 3] = t4.w;
    }
    for (int row = gw; row < BB * TT; row += third) {
      const int q = question[row];                     // wave-uniform
      const float* __restrict__ krow = k_emb + (size_t)q * 64;
      float l0 = 0.f, l1 = 0.f, l2 = 0.f, l3 = 0.f;
#pragma unroll
      for (int i = 0; i < 64; i += 4) {
        const float4 kv = *(const float4*)(krow + i);  // uniform -> s_load
        l0 = fmaf(kv.x, mk[i], l0);
        l1 = fmaf(kv.y, mk[i + 1], l1);
        l2 = fmaf(kv.z, mk[i + 2], l2);
        l3 = fmaf(kv.w, mk[i + 3], l3);
      }
      const float lm = (l0 + l1) + (l2 + l3);
      float lv = (lane < MM) ? lm : -3.4e38f;
#pragma unroll
      for (int off = 32; off > 0; off >>= 1) lv = fmaxf(lv, __shfl_xor(lv, off));
      float pe = (lane < MM) ? __expf(lm - lv) : 0.f;
      float ss = pe;
#pragma unroll
      for (int off = 32; off > 0; off >>= 1) ss += __shfl_xor(ss, off);
      if (lane < MM) w_buf[(size_t)row * WPAD + lane] = pe / ss;
    }
  } else if (gw < 2 * third) {            // role: e
    float ew[64];
#pragma unroll
    for (int i = 0; i < 64; ++i) ew[i] = e_W[i * 64 + lane];
    const float eb = e_b[lane];
    for (int row = gw - third; row < BB * TT; row += third) {
      const int q = question[row];
      const int r = response[row];
      const float mf = (mask[row] == 1.0f) ? 1.0f : 0.0f;
      const float* __restrict__ vrow = v_emb + ((size_t)q + (size_t)QN * r) * 64;
      float e0 = eb, e1 = 0.f;
#pragma unroll
      for (int i = 0; i < 64; i += 2) {
        const float2 vv = *(const float2*)(vrow + i);  // uniform -> s_load
        e0 = fmaf(vv.x, ew[i], e0);
        e1 = fmaf(vv.y, ew[i + 1], e1);
      }
      const float se = e0 + e1;
      e_buf[(size_t)row * 64 + lane] = mf / (1.f + __expf(-se));
    }
  } else {                                // role: a
    const int stride = NWv - 2 * third;
    float aw[64];
#pragma unroll
    for (int i = 0; i < 64; ++i) aw[i] = a_W[i * 64 + lane];
    const float ab = a_b[lane];
    for (int row = gw - 2 * third; row < BB * TT; row += stride) {
      const int q = question[row];
      const int r = response[row];
      const float mf = (mask[row] == 1.0f) ? 1.0f : 0.0f;
      const float* __restrict__ vrow = v_emb + ((size_t)q + (size_t)QN * r) * 64;
      float a0 = ab, a1 = 0.f;
#pragma unroll
      for (int i = 0; i < 64; i += 2) {
        const float2 vv = *(const float2*)(vrow + i);
        a0 = fmaf(vv.x, aw[i], a0);
        a1 = fmaf(vv.y, aw[i + 1], a1);
      }
      const float sa = a0 + a1;
      const float t2 = __expf(2.f * sa);
      a_buf[(size_t)row * 64 + lane] = mf * (1.f - 2.f / (t2 + 1.f));
    }
  }
}

// ---- Phase A: per-(b,chunk,mgroup) composed affine (A,B) per (m,d).
__device__ __forceinline__ void phaseA(
    int gw, int NWv, int lane, int logC, int L,
    const float* __restrict__ w_buf, const float* __restrict__ e_buf,
    const float* __restrict__ a_buf, float* __restrict__ AB) {
  const int C = 1 << logC;
  for (int u2 = gw; u2 < BB * C * 2; u2 += NWv) {
    const int g = u2 & 1;
    const int unit = u2 >> 1;                          // b*C + c
    const int b = unit >> logC;
    const int c = unit & (C - 1);
    float Am[MG], Bm[MG];
#pragma unroll
    for (int m = 0; m < MG; ++m) { Am[m] = 1.f; Bm[m] = 0.f; }
    const size_t rowbase = (size_t)b * TT + c * L;
#pragma unroll 2
    for (int j = 0; j < L; ++j) {
      const size_t row = rowbase + j;
      const float ed = e_buf[row * 64 + lane];
      const float ad = a_buf[row * 64 + lane];
      const float* __restrict__ wr = w_buf + row * WPAD + g * MG; // uniform
#pragma unroll
      for (int m = 0; m < MG; ++m) {
        const float wm = wr[m];
        const float al = fmaf(-wm, ed, 1.0f);
        const float be = wm * ad;
        Am[m] *= al;
        Bm[m] = fmaf(Bm[m], al, be);
      }
    }
    float* __restrict__ abp = AB + (size_t)unit * 6400 + (g * MG) * 128 + lane * 2;
#pragma unroll
    for (int m = 0; m < MG; ++m) {
      float2 o; o.x = Am[m]; o.y = Bm[m];
      *(float2*)(abp + m * 128) = o;
    }
  }
}

// ---- Phase B: sequential over C chunks, parallel over B*M*D elements.
__device__ __forceinline__ void phaseB(
    int tid, int NT, const float* __restrict__ AB,
    const float* __restrict__ Mv0, float* __restrict__ entry, int C) {
  for (int idx = tid; idx < BB * MM * 64; idx += NT) {
    const int b = idx / (MM * 64);
    const int r = idx - b * (MM * 64);                 // m*64 + d
    float s = Mv0[r];
    const float* __restrict__ abp = AB + (size_t)b * C * 6400 + (size_t)r * 2;
    float* __restrict__ ep = entry + (size_t)b * C * 3200 + r;
    if (C == 32) {
      float2 ab[32];
#pragma unroll
      for (int c = 0; c < 32; ++c)
        ab[c] = *(const float2*)(abp + (size_t)c * 6400);
#pragma unroll
      for (int c = 0; c < 32; ++c) {
        ep[(size_t)c * 3200] = s;
        s = fmaf(ab[c].x, s, ab[c].y);
      }
    } else {
      float2 cur = *(const float2*)(abp);
      for (int c = 0; c < C; ++c) {
        ep[(size_t)c * 3200] = s;
        float2 nxt; nxt.x = 1.f; nxt.y = 0.f;
        if (c + 1 < C) nxt = *(const float2*)(abp + (size_t)(c + 1) * 6400);
        s = fmaf(cur.x, s, cur.y);
        cur = nxt;
      }
    }
  }
}

// ---- Phase C: replay each chunk from its entry state, emitting partial reads.
__device__ __forceinline__ void phaseC(
    int gw, int NWv, int lane, int logC, int L, int useChunks,
    const float* __restrict__ w_buf, const float* __restrict__ e_buf,
    const float* __restrict__ a_buf, const float* __restrict__ entry,
    const float* __restrict__ Mv0, float* __restrict__ read2) {
  const int C = 1 << logC;
  const size_t RN = (size_t)BB * (TT - 1) * 64;
  for (int u2 = gw; u2 < BB * C * 2; u2 += NWv) {
    const int g = u2 & 1;
    const int unit = u2 >> 1;                          // b*C + c
    const int b = unit >> logC;
    const int c = unit & (C - 1);
    float s[MG];
    if (!useChunks) {
#pragma unroll
      for (int m = 0; m < MG; ++m) s[m] = Mv0[(g * MG + m) * 64 + lane];
    } else {
      const float* __restrict__ ep =
          entry + (size_t)unit * 3200 + (g * MG) * 64 + lane;
#pragma unroll
      for (int m = 0; m < MG; ++m) s[m] = ep[m * 64];
    }
    const int t0 = c * L;
    float* __restrict__ rb = read2 + (size_t)g * RN;
    int j0 = 0;
    if (t0 == 0) {
      // step t=0: update only, no read emitted
      const size_t row = (size_t)b * TT;
      const float ed = e_buf[row * 64 + lane];
      const float ad = a_buf[row * 64 + lane];
      const float* __restrict__ wr = w_buf + row * WPAD + g * MG;
#pragma unroll
      for (int m = 0; m < MG; ++m)
        s[m] = fmaf(wr[m], fmaf(-s[m], ed, ad), s[m]);
      j0 = 1;
    }
#pragma unroll 2
    for (int j = j0; j < L; ++j) {
      const int t = t0 + j;
      const size_t row = (size_t)b * TT + t;
      const float ed = e_buf[row * 64 + lane];
      const float ad = a_buf[row * 64 + lane];
      const float* __restrict__ wr = w_buf + row * WPAD + g * MG; // uniform
      float a0 = 0.f, a1 = 0.f;
#pragma unroll
      for (int m = 0; m < MG - 1; m += 2) {
        a0 = fmaf(wr[m], s[m], a0);
        a1 = fmaf(wr[m + 1], s[m + 1], a1);
      }
      a0 = fmaf(wr[MG - 1], s[MG - 1], a0);            // MG=25 is odd
      rb[((size_t)b * (TT - 1) + (t - 1)) * 64 + lane] = a0 + a1;
#pragma unroll
      for (int m = 0; m < MG; ++m)
        s[m] = fmaf(wr[m], fmaf(-s[m], ed, ad), s[m]);
    }
  }
}

// ---- Phase D: f = tanh([read | k_{t+1}] @ f_W + f_b); p = f @ p_W + p_b.
__device__ __forceinline__ void phaseD(
    int gw, int NWv, int lane, int wslot,
    const int* __restrict__ question, const float* __restrict__ k_emb,
    const float* __restrict__ read2,
    const float* __restrict__ f_W, const float* __restrict__ f_b,
    const float* __restrict__ p_W, const float* __restrict__ p_b,
    float* __restrict__ out) {
  __shared__ float pbuf[2][2][64];                     // [parity][pair][lane]
  const size_t RN = (size_t)BB * (TT - 1) * 64;
  const int UD = BB * (TT - 1) * 2;                    // rows x 2 roles
  const int iters = (UD + NWv - 1) / NWv;              // padded: all waves
  const int g = wslot & 1;
  float fw[64];
#pragma unroll
  for (int i = 0; i < 64; ++i) fw[i] = f_W[(g * 64 + i) * 64 + lane];
  const float fb = f_b[lane];
  const float pw = p_W[lane];
  const float pb = p_b[0];
  for (int it = 0; it < iters; ++it) {
    const int u = gw + it * NWv;
    const bool active = (u < UD);
    const int row = u >> 1;
    float partial = 0.f;
    if (active) {
      if (g == 0) {                                    // read-half of f_W
        const float* __restrict__ r0 = read2 + (size_t)row * 64;
        const float* __restrict__ r1 = r0 + RN;
        float f0 = 0.f, f1 = 0.f, f2 = 0.f, f3 = 0.f;
#pragma unroll
        for (int i = 0; i < 64; i += 4) {
          const float4 x0 = *(const float4*)(r0 + i);  // uniform -> s_load
          const float4 x1 = *(const float4*)(r1 + i);
          f0 = fmaf(x0.x + x1.x, fw[i], f0);
          f1 = fmaf(x0.y + x1.y, fw[i + 1], f1);
          f2 = fmaf(x0.z + x1.z, fw[i + 2], f2);
          f3 = fmaf(x0.w + x1.w, fw[i + 3], f3);
        }
        partial = (f0 + f1) + (f2 + f3);
      } else {                                         // k-half of f_W
        const int b = row / (TT - 1);
        const int tp = row - b * (TT - 1);
        const int qn = question[b * TT + tp + 1];      // wave-uniform
        const float* __restrict__ krow = k_emb + (size_t)qn * 64;
        float f0 = 0.f, f1 = 0.f, f2 = 0.f, f3 = 0.f;
#pragma unroll
        for (int i = 0; i < 64; i += 4) {
          const float4 kv = *(const float4*)(krow + i);
          f0 = fmaf(kv.x, fw[i], f0);
          f1 = fmaf(kv.y, fw[i + 1], f1);
          f2 = fmaf(kv.z, fw[i + 2], f2);
          f3 = fmaf(kv.w, fw[i + 3], f3);
        }
        partial = (f0 + f1) + (f2 + f3);
      }
    }
    const int pr = it & 1;                             // LDS parity dbuf
    if (active && g == 1) pbuf[pr][wslot >> 1][lane] = partial;
    __syncthreads();
    if (active && g == 0) {
      const float fsum = partial + pbuf[pr][wslot >> 1][lane] + fb;
      const float t2 = __expf(2.f * fsum);
      const float fv = 1.f - 2.f / (t2 + 1.f);         // tanh
      float acc = fv * pw;
#pragma unroll
      for (int off = 32; off > 0; off >>= 1) acc += __shfl_xor(acc, off);
      if (lane == 0) out[row] = acc + pb;
    }
  }
}

// ===========================================================================
// Fused cooperative kernel: one dispatch for the whole pipeline.
// KEY CHANGE vs round 2: no min-waves floor in __launch_bounds__, plus
// amdgpu_waves_per_eu(2,4) so the backend does NOT squeeze to 64 VGPRs for
// 8 waves/EU (round 2: VGPR=64 -> arrays demoted, zero load ILP, 737 us).
// Target: ~110-170 VGPR, 3-4 blocks/CU; grid sized by occupancy query.
// ===========================================================================
__global__ __attribute__((amdgpu_waves_per_eu(2, 4))) __launch_bounds__(256)
void kFused(
    const int* __restrict__ question, const int* __restrict__ response,
    const float* __restrict__ mask,
    const float* __restrict__ k_emb, const float* __restrict__ v_emb,
    const float* __restrict__ Mk, const float* __restrict__ Mv0,
    const float* __restrict__ e_W, const float* __restrict__ e_b,
    const float* __restrict__ a_W, const float* __restrict__ a_b,
    const float* __restrict__ f_W, const float* __restrict__ f_b,
    const float* __restrict__ p_W, const float* __restrict__ p_b,
    float* __restrict__ out,
    float* __restrict__ w_buf, float* __restrict__ e_buf,
    float* __restrict__ a_buf, float* __restrict__ read2,
    float* __restrict__ AB, float* __restrict__ entry,
    int logC, int L, int useChunks) {
  cg::grid_group grid = cg::this_grid();
  const int lane = (int)(threadIdx.x & 63);
  const int wslot = __builtin_amdgcn_readfirstlane((int)(threadIdx.x >> 6));
  const int gw = blockIdx.x * 4 + wslot;
  const int NWv = gridDim.x * 4;

  phase0(gw, NWv, lane, question, response, mask, k_emb, v_emb, Mk,
         e_W, e_b, a_W, a_b, w_buf, e_buf, a_buf);
  __threadfence();
  grid.sync();

  if (useChunks) {                                     // grid-uniform branch
    phaseA(gw, NWv, lane, logC, L, w_buf, e_buf, a_buf, AB);
    __threadfence();
    grid.sync();
    phaseB(blockIdx.x * 256 + (int)threadIdx.x, gridDim.x * 256,
           AB, Mv0, entry, 1 << logC);
    __threadfence();
    grid.sync();
  }

  phaseC(gw, NWv, lane, logC, L, useChunks, w_buf, e_buf, a_buf,
         entry, Mv0, read2);
  __threadfence();
  grid.sync();

  phaseD(gw, NWv, lane, wslot, question, k_emb, read2,
         f_W, f_b, p_W, p_b, out);
}

// ===========================================================================
// Discrete-kernel fallback (used only if cooperative launch fails).
// ===========================================================================
__global__ __launch_bounds__(256) void kP0(
    const int* __restrict__ question, const int* __restrict__ response,
    const float* __restrict__ mask,
    const float* __restrict__ k_emb, const float* __restrict__ v_emb,
    const float* __restrict__ Mk,
    const float* __restrict__ e_W, const float* __restrict__ e_b,
    const float* __restrict__ a_W, const float* __restrict__ a_b,
    float* __restrict__ w_buf, float* __restrict__ e_buf,
    float* __restrict__ a_buf) {
  const int lane = (int)(threadIdx.x & 63);
  const int wslot = __builtin_amdgcn_readfirstlane((int)(threadIdx.x >> 6));
  phase0(blockIdx.x * 4 + wslot, gridDim.x * 4, lane, question, response, mask,
         k_emb, v_emb, Mk, e_W, e_b, a_W, a_b, w_buf, e_buf, a_buf);
}

__global__ __launch_bounds__(256) void kPA(
    const float* __restrict__ w_buf, const float* __restrict__ e_buf,
    const float* __restrict__ a_buf, float* __restrict__ AB, int logC, int L) {
  const int lane = (int)(threadIdx.x & 63);
  const int wslot = __builtin_amdgcn_readfirstlane((int)(threadIdx.x >> 6));
  phaseA(blockIdx.x * 4 + wslot, gridDim.x * 4, lane, logC, L,
         w_buf, e_buf, a_buf, AB);
}

__global__ __launch_bounds__(256) void kPB(
    const float* __restrict__ AB, const float* __restrict__ Mv0,
    float* __restrict__ entry, int C) {
  phaseB(blockIdx.x * 256 + (int)threadIdx.x, gridDim.x * 256,
         AB, Mv0, entry, C);
}

__global__ __launch_bounds__(256) void kPC(
    const float* __restrict__ w_buf, const float* __restrict__ e_buf,
    const float* __restrict__ a_buf, const float* __restrict__ entry,
    const float* __restrict__ Mv0, float* __restrict__ read2,
    int logC, int L, int useChunks) {
  const int lane = (int)(threadIdx.x & 63);
  const int wslot = __builtin_amdgcn_readfirstlane((int)(threadIdx.x >> 6));
  phaseC(blockIdx.x * 4 + wslot, gridDim.x * 4, lane, logC, L, useChunks,
         w_buf, e_buf, a_buf, entry, Mv0, read2);
}

__global__ __launch_bounds__(256) void kPD(
    const int* __restrict__ question, const float* __restrict__ k_emb,
    const float* __restrict__ read2,
    const float* __restrict__ f_W, const float* __restrict__ f_b,
    const float* __restrict__ p_W, const float* __restrict__ p_b,
    float* __restrict__ out) {
  const int lane = (int)(threadIdx.x & 63);
  const int wslot = __builtin_amdgcn_readfirstlane((int)(threadIdx.x >> 6));
  phaseD(blockIdx.x * 4 + wslot, gridDim.x * 4, lane, wslot,
         question, k_emb, read2, f_W, f_b, p_W, p_b, out);
}

// ---------------------------------------------------------------------------
extern "C" void kernel_launch(void* const* d_in, const int* in_sizes, int n_in,
                              void* d_out, int out_size, void* d_ws, size_t ws_size,
                              hipStream_t stream) {
  const int*   question = (const int*)d_in[0];
  const int*   response = (const int*)d_in[1];
  const float* mask     = (const float*)d_in[2];
  const float* k_emb    = (const float*)d_in[3];
  const float* v_emb    = (const float*)d_in[4];
  const float* Mk       = (const float*)d_in[5];
  const float* Mv0      = (const float*)d_in[6];
  const float* e_W      = (const float*)d_in[7];
  const float* e_b      = (const float*)d_in[8];
  const float* a_W      = (const float*)d_in[9];
  const float* a_b      = (const float*)d_in[10];
  const float* f_W      = (const float*)d_in[11];
  const float* f_b      = (const float*)d_in[12];
  const float* p_W      = (const float*)d_in[13];
  const float* p_b      = (const float*)d_in[14];
  float* out = (float*)d_out;

  // workspace layout (floats): planar e/a for fully-coalesced role stores
  const size_t wN  = (size_t)BB * TT * WPAD;       // 1,703,936
  const size_t eN  = (size_t)BB * TT * 64;         // 2,097,152
  const size_t r2N = 2ull * BB * (TT - 1) * 64;    // 4,186,112
  float* ws = (float*)d_ws;
  float* w_buf  = ws;
  float* e_buf  = w_buf + wN;
  float* a_buf  = e_buf + eN;
  float* read2  = a_buf + eN;
  float* AB_arr = read2 + r2N;
  const size_t baseN = wN + 2 * eN + r2N;

  // choose the largest chunk count C that fits the workspace
  // per-C cost: AB (6400*B*C) + entry (3200*B*C) floats
  int C = 32, logC = 5;
  while (C >= 2) {
    const size_t need = (baseN + 9600ull * BB * C) * sizeof(float);
    if (need <= ws_size) break;
    C >>= 1; logC -= 1;
  }
  int useChunks = (C >= 2);
  if (!useChunks) { C = 1; logC = 0; }
  int L = TT / C;
  float* entry = AB_arr + 6400ull * BB * C;

  // grid size for cooperative co-residency (one-time host-only query)
  static int g_nb = 0;
  if (g_nb == 0) {
    int occ = 0;
    if (hipOccupancyMaxActiveBlocksPerMultiprocessor(
            &occ, (const void*)kFused, 256, 0) != hipSuccess || occ < 1)
      occ = 1;
    long nb = (long)occ * 256;   // 256 CUs on MI355X (gfx950)
    if (nb > 1024) nb = 1024;
    if (nb < 4) nb = 4;
    g_nb = (int)nb;
  }

  void* args[] = {
    (void*)&question, (void*)&response, (void*)&mask, (void*)&k_emb,
    (void*)&v_emb, (void*)&Mk, (void*)&Mv0, (void*)&e_W, (void*)&e_b,
    (void*)&a_W, (void*)&a_b, (void*)&f_W, (void*)&f_b, (void*)&p_W,
    (void*)&p_b, (void*)&out, (void*)&w_buf, (void*)&e_buf, (void*)&a_buf,
    (void*)&read2, (void*)&AB_arr, (void*)&entry,
    (void*)&logC, (void*)&L, (void*)&useChunks
  };
  hipError_t err = hipLaunchCooperativeKernel(
      (const void*)kFused, dim3(g_nb), dim3(256), args, 0, stream);

  if (err != hipSuccess) {
    // fallback: discrete phase kernels (same device code, normal launches)
    const int ublocks = (BB * C * 2 + 3) / 4;
    hipLaunchKernelGGL(kP0, dim3(1024), dim3(256), 0, stream,
                       question, response, mask, k_emb, v_emb, Mk,
                       e_W, e_b, a_W, a_b, w_buf, e_buf, a_buf);
    if (useChunks) {
      hipLaunchKernelGGL(kPA, dim3(ublocks), dim3(256), 0, stream,
                         w_buf, e_buf, a_buf, AB_arr, logC, L);
      hipLaunchKernelGGL(kPB, dim3((BB * MM * 64 + 255) / 256), dim3(256), 0,
                         stream, AB_arr, Mv0, entry, C);
    }
    hipLaunchKernelGGL(kPC, dim3(ublocks), dim3(256), 0, stream,
                       w_buf, e_buf, a_buf, entry, Mv0, read2,
                       logC, L, useChunks);
    hipLaunchKernelGGL(kPD, dim3(1024), dim3(256), 0, stream,
                       question, k_emb, read2, f_W, f_b, p_W, p_b, out);
  }
}

// Round 4
// 297.397 us; speedup vs baseline: 2.4779x; 2.1229x over previous
//
#include <hip/hip_runtime.h>
#include <cstddef>

// Problem constants (from reference)
#define QN 10000
#define DD 64
#define MM 50
#define BB 64
#define TT 512
#define WPAD 52   // padded w row stride in floats (208 B -> 16B-aligned rows)
#define MG 25     // m's per wave in the 2-way m-split compose kernel

// ===========================================================================
// kPre: one dispatch for all per-timestep precompute.
//   role w: w = softmax(k @ Mk^T)          (waves [0, NW/3))
//   role e: e = sigmoid(v@e_W+e_b) * mask  (waves [NW/3, 2NW/3))
//   role a: a = tanh(v@a_W+a_b) * mask     (waves [2NW/3, NW))
// Mask folded into e/a => downstream scan updates are branchless
// (mask!=1 -> e=a=0 -> alpha=1,beta=0 -> identity step).
// ===========================================================================
__global__ __launch_bounds__(256) void kPre(
    const int* __restrict__ question, const int* __restrict__ response,
    const float* __restrict__ mask,
    const float* __restrict__ k_emb, const float* __restrict__ v_emb,
    const float* __restrict__ Mk,
    const float* __restrict__ e_W, const float* __restrict__ e_b,
    const float* __restrict__ a_W, const float* __restrict__ a_b,
    float* __restrict__ w_buf, float* __restrict__ e_buf,
    float* __restrict__ a_buf) {
  const int lane = (int)(threadIdx.x & 63);
  const int wslot = __builtin_amdgcn_readfirstlane((int)(threadIdx.x >> 6));
  const int gw = blockIdx.x * 4 + wslot;
  const int NW = gridDim.x * 4;
  const int third = NW / 3;

  if (gw < third) {                       // ---- role: w (softmax)
    float mk[64];
    const int mrow = lane < MM ? lane : (MM - 1);
#pragma unroll
    for (int i = 0; i < 64; i += 4) {
      const float4 t4 = *(const float4*)(Mk + mrow * 64 + i);
      mk[i] = t4.x; mk[i + 1] = t4.y; mk[i + 2] = t4.z; mk[i + 3] = t4.w;
    }
    for (int row = gw; row < BB * TT; row += third) {
      const int q = question[row];                     // wave-uniform
      const float* __restrict__ krow = k_emb + (size_t)q * 64;
      float l0 = 0.f, l1 = 0.f, l2 = 0.f, l3 = 0.f;
#pragma unroll
      for (int i = 0; i < 64; i += 4) {
        const float4 kv = *(const float4*)(krow + i);  // uniform -> s_load
        l0 = fmaf(kv.x, mk[i], l0);
        l1 = fmaf(kv.y, mk[i + 1], l1);
        l2 = fmaf(kv.z, mk[i + 2], l2);
        l3 = fmaf(kv.w, mk[i + 3], l3);
      }
      const float lm = (l0 + l1) + (l2 + l3);
      float lv = (lane < MM) ? lm : -3.4e38f;
#pragma unroll
      for (int off = 32; off > 0; off >>= 1) lv = fmaxf(lv, __shfl_xor(lv, off));
      float pe = (lane < MM) ? __expf(lm - lv) : 0.f;
      float ss = pe;
#pragma unroll
      for (int off = 32; off > 0; off >>= 1) ss += __shfl_xor(ss, off);
      if (lane < MM) w_buf[(size_t)row * WPAD + lane] = pe / ss;
    }
  } else if (gw < 2 * third) {            // ---- role: e
    float ew[64];
#pragma unroll
    for (int i = 0; i < 64; ++i) ew[i] = e_W[i * 64 + lane];
    const float eb = e_b[lane];
    for (int row = gw - third; row < BB * TT; row += third) {
      const int q = question[row];
      const int r = response[row];
      const float mf = (mask[row] == 1.0f) ? 1.0f : 0.0f;
      const float* __restrict__ vrow = v_emb + ((size_t)q + (size_t)QN * r) * 64;
      float e0 = eb, e1 = 0.f;
#pragma unroll
      for (int i = 0; i < 64; i += 2) {
        const float2 vv = *(const float2*)(vrow + i);  // uniform -> s_load
        e0 = fmaf(vv.x, ew[i], e0);
        e1 = fmaf(vv.y, ew[i + 1], e1);
      }
      const float se = e0 + e1;
      e_buf[(size_t)row * 64 + lane] = mf / (1.f + __expf(-se));
    }
  } else {                                // ---- role: a
    const int stride = NW - 2 * third;
    float aw[64];
#pragma unroll
    for (int i = 0; i < 64; ++i) aw[i] = a_W[i * 64 + lane];
    const float ab = a_b[lane];
    for (int row = gw - 2 * third; row < BB * TT; row += stride) {
      const int q = question[row];
      const int r = response[row];
      const float mf = (mask[row] == 1.0f) ? 1.0f : 0.0f;
      const float* __restrict__ vrow = v_emb + ((size_t)q + (size_t)QN * r) * 64;
      float a0 = ab, a1 = 0.f;
#pragma unroll
      for (int i = 0; i < 64; i += 2) {
        const float2 vv = *(const float2*)(vrow + i);
        a0 = fmaf(vv.x, aw[i], a0);
        a1 = fmaf(vv.y, aw[i + 1], a1);
      }
      const float sa = a0 + a1;
      const float t2 = __expf(2.f * sa);
      a_buf[(size_t)row * 64 + lane] = mf * (1.f - 2.f / (t2 + 1.f));
    }
  }
}

// ===========================================================================
// kA: per-(b,chunk,mgroup) composed affine (A,B) per (m,d). One wave per
// unit2=(b*C+c)*2+g; lane=d; 25 m's in registers. Branchless inner loop.
//   AB layout: [b][c][m][d][{A,B}] (float2 per (m,d)) -> unit*6400 floats.
// ===========================================================================
__global__ __launch_bounds__(256) void kA_chunk(
    const float* __restrict__ w_buf, const float* __restrict__ e_buf,
    const float* __restrict__ a_buf, float* __restrict__ AB, int logC, int L) {
  const int lane = (int)(threadIdx.x & 63);
  const int wslot = __builtin_amdgcn_readfirstlane((int)(threadIdx.x >> 6));
  const int NW = gridDim.x * 4;
  const int C = 1 << logC;
  for (int u2 = blockIdx.x * 4 + wslot; u2 < BB * C * 2; u2 += NW) {
    const int g = u2 & 1;
    const int unit = u2 >> 1;                          // b*C + c
    const int b = unit >> logC;
    const int c = unit & (C - 1);
    float Am[MG], Bm[MG];
#pragma unroll
    for (int m = 0; m < MG; ++m) { Am[m] = 1.f; Bm[m] = 0.f; }
    const size_t rowbase = (size_t)b * TT + c * L;
#pragma unroll 2
    for (int j = 0; j < L; ++j) {
      const size_t row = rowbase + j;
      const float ed = e_buf[row * 64 + lane];
      const float ad = a_buf[row * 64 + lane];
      const float* __restrict__ wr = w_buf + row * WPAD + g * MG; // uniform
#pragma unroll
      for (int m = 0; m < MG; ++m) {
        const float wm = wr[m];
        const float al = fmaf(-wm, ed, 1.0f);
        const float be = wm * ad;
        Am[m] *= al;
        Bm[m] = fmaf(Bm[m], al, be);
      }
    }
    float* __restrict__ abp = AB + (size_t)unit * 6400 + (g * MG) * 128 + lane * 2;
#pragma unroll
    for (int m = 0; m < MG; ++m) {
      float2 o; o.x = Am[m]; o.y = Bm[m];
      *(float2*)(abp + m * 128) = o;
    }
  }
}

// ===========================================================================
// kB: sequential over C chunks, parallel over B*M*D = 204,800 elements.
// C==32 fast path: all 32 coefficient pairs loaded up front (one latency
// exposure). entry[c] = state before chunk c.
// ===========================================================================
__global__ __launch_bounds__(256) void kB_entry(
    const float* __restrict__ AB, const float* __restrict__ Mv0,
    float* __restrict__ entry, int C) {
  const int NT = gridDim.x * 256;
  for (int idx = blockIdx.x * 256 + (int)threadIdx.x; idx < BB * MM * 64;
       idx += NT) {
    const int b = idx / (MM * 64);
    const int r = idx - b * (MM * 64);                 // m*64 + d
    float s = Mv0[r];
    const float* __restrict__ abp = AB + (size_t)b * C * 6400 + (size_t)r * 2;
    float* __restrict__ ep = entry + (size_t)b * C * 3200 + r;
    if (C == 32) {
      float2 ab[32];
#pragma unroll
      for (int c = 0; c < 32; ++c)
        ab[c] = *(const float2*)(abp + (size_t)c * 6400);
#pragma unroll
      for (int c = 0; c < 32; ++c) {
        ep[(size_t)c * 3200] = s;
        s = fmaf(ab[c].x, s, ab[c].y);
      }
    } else {
      float2 cur = *(const float2*)(abp);
      for (int c = 0; c < C; ++c) {
        ep[(size_t)c * 3200] = s;
        float2 nxt; nxt.x = 1.f; nxt.y = 0.f;
        if (c + 1 < C) nxt = *(const float2*)(abp + (size_t)(c + 1) * 6400);
        s = fmaf(cur.x, s, cur.y);
        cur = nxt;
      }
    }
  }
}

// ===========================================================================
// kD: fused replay + output MLP. One wave per unit (b*C+c); lane = d;
// FULL 50-m state in registers. Per row t>=1:
//   read_d = sum_m w[m] * s[m][d]                    (in-register, lane=d)
//   f[d]   = tanh( sum_i read_i*fW[i][d]  (readlane broadcast of lane i)
//                + sum_i k_i  *fW[64+i][d] (k_i wave-uniform scalar)
//                + f_b[d] )
//   out[row] = dot(f, p_W) + p_b                     (shfl reduce)
// Then branchless state update. No read2 buffer, no separate k3 dispatch.
// VGPR ~195 (fw[128]+s[50]) -> waves_per_eu(1,2) so the allocator is NOT
// squeezed (round-2/3 lesson: backend will demote arrays otherwise).
// ===========================================================================
__global__ __attribute__((amdgpu_waves_per_eu(1, 2))) __launch_bounds__(256)
void kD_readout(
    const int* __restrict__ question,
    const float* __restrict__ w_buf, const float* __restrict__ e_buf,
    const float* __restrict__ a_buf, const float* __restrict__ entry,
    const float* __restrict__ Mv0, const float* __restrict__ k_emb,
    const float* __restrict__ f_W, const float* __restrict__ f_b,
    const float* __restrict__ p_W, const float* __restrict__ p_b,
    float* __restrict__ out, int logC, int L, int useChunks) {
  const int lane = (int)(threadIdx.x & 63);
  const int wslot = __builtin_amdgcn_readfirstlane((int)(threadIdx.x >> 6));
  const int NW = gridDim.x * 4;
  const int C = 1 << logC;

  // invariant weights (per-wave, loaded once)
  float fw1[64], fw2[64];
#pragma unroll
  for (int i = 0; i < 64; ++i) {
    fw1[i] = f_W[i * 64 + lane];          // read-half rows 0..63
    fw2[i] = f_W[(64 + i) * 64 + lane];   // k-half rows 64..127
  }
  const float fb = f_b[lane];
  const float pw = p_W[lane];
  const float pb = p_b[0];

  for (int unit = blockIdx.x * 4 + wslot; unit < BB * C; unit += NW) {
    const int b = unit >> logC;
    const int c = unit & (C - 1);
    float s[MM];
    if (useChunks) {
      const float* __restrict__ ep = entry + (size_t)unit * 3200 + lane;
#pragma unroll
      for (int m = 0; m < MM; ++m) s[m] = ep[m * 64];
    } else {
#pragma unroll
      for (int m = 0; m < MM; ++m) s[m] = Mv0[m * 64 + lane];
    }
    const int t0 = c * L;
    for (int j = 0; j < L; ++j) {
      const int t = t0 + j;
      const size_t row = (size_t)b * TT + t;
      const float* __restrict__ wr = w_buf + row * WPAD;  // uniform s_loads
      const float ed = e_buf[row * 64 + lane];
      const float ad = a_buf[row * 64 + lane];

      if (t >= 1) {                                    // wave-uniform branch
        // read_d = sum_m w[m] s[m][d]
        float r0 = 0.f, r1 = 0.f;
#pragma unroll
        for (int m = 0; m < MM; m += 2) {
          r0 = fmaf(wr[m], s[m], r0);
          r1 = fmaf(wr[m + 1], s[m + 1], r1);
        }
        const float rd = r0 + r1;
        // f = tanh(read @ fW1 + k @ fW2 + fb)
        const int qn = question[row];                  // wave-uniform
        const float* __restrict__ krow = k_emb + (size_t)qn * 64;
        float f0 = fb, f1 = 0.f, f2 = 0.f, f3 = 0.f;
#pragma unroll
        for (int i = 0; i < 64; i += 4) {
          f0 = fmaf(__shfl(rd, i), fw1[i], f0);        // readlane broadcast
          f1 = fmaf(__shfl(rd, i + 1), fw1[i + 1], f1);
          f2 = fmaf(__shfl(rd, i + 2), fw1[i + 2], f2);
          f3 = fmaf(__shfl(rd, i + 3), fw1[i + 3], f3);
        }
#pragma unroll
        for (int i = 0; i < 64; i += 4) {
          const float4 kv = *(const float4*)(krow + i); // uniform -> s_load
          f0 = fmaf(kv.x, fw2[i], f0);
          f1 = fmaf(kv.y, fw2[i + 1], f1);
          f2 = fmaf(kv.z, fw2[i + 2], f2);
          f3 = fmaf(kv.w, fw2[i + 3], f3);
        }
        const float fsum = (f0 + f1) + (f2 + f3);
        const float t2 = __expf(2.f * fsum);
        const float fv = 1.f - 2.f / (t2 + 1.f);       // tanh
        float acc = fv * pw;
#pragma unroll
        for (int off = 32; off > 0; off >>= 1) acc += __shfl_xor(acc, off);
        if (lane == 0) out[(size_t)b * (TT - 1) + (t - 1)] = acc + pb;
      }
      // branchless state update (mask folded into e/a)
#pragma unroll
      for (int m = 0; m < MM; ++m)
        s[m] = fmaf(wr[m], fmaf(-s[m], ed, ad), s[m]);
    }
  }
}

// ---------------------------------------------------------------------------
extern "C" void kernel_launch(void* const* d_in, const int* in_sizes, int n_in,
                              void* d_out, int out_size, void* d_ws, size_t ws_size,
                              hipStream_t stream) {
  const int*   question = (const int*)d_in[0];
  const int*   response = (const int*)d_in[1];
  const float* mask     = (const float*)d_in[2];
  const float* k_emb    = (const float*)d_in[3];
  const float* v_emb    = (const float*)d_in[4];
  const float* Mk       = (const float*)d_in[5];
  const float* Mv0      = (const float*)d_in[6];
  const float* e_W      = (const float*)d_in[7];
  const float* e_b      = (const float*)d_in[8];
  const float* a_W      = (const float*)d_in[9];
  const float* a_b      = (const float*)d_in[10];
  const float* f_W      = (const float*)d_in[11];
  const float* f_b      = (const float*)d_in[12];
  const float* p_W      = (const float*)d_in[13];
  const float* p_b      = (const float*)d_in[14];
  float* out = (float*)d_out;

  // workspace layout (floats)
  const size_t wN = (size_t)BB * TT * WPAD;        // 1,703,936
  const size_t eN = (size_t)BB * TT * 64;          // 2,097,152
  float* ws = (float*)d_ws;
  float* w_buf  = ws;
  float* e_buf  = w_buf + wN;
  float* a_buf  = e_buf + eN;
  float* AB_arr = a_buf + eN;
  const size_t baseN = wN + 2 * eN;                // 5,898,240 floats

  // choose the largest chunk count C that fits the workspace
  // per-C cost: AB (6400*B*C) + entry (3200*B*C) floats
  int C = 32, logC = 5;
  while (C >= 2) {
    const size_t need = (baseN + 9600ull * BB * C) * sizeof(float);
    if (need <= ws_size) break;
    C >>= 1; logC -= 1;
  }
  int useChunks = (C >= 2);
  if (!useChunks) { C = 1; logC = 0; }
  const int L = TT / C;
  float* entry = AB_arr + 6400ull * BB * C;

  // 4 dispatches, no cooperative launch, no grid.sync
  hipLaunchKernelGGL(kPre, dim3(2048), dim3(256), 0, stream,
                     question, response, mask, k_emb, v_emb, Mk,
                     e_W, e_b, a_W, a_b, w_buf, e_buf, a_buf);
  if (useChunks) {
    const int ublocksA = (BB * C * 2 + 3) / 4;
    hipLaunchKernelGGL(kA_chunk, dim3(ublocksA), dim3(256), 0, stream,
                       w_buf, e_buf, a_buf, AB_arr, logC, L);
    hipLaunchKernelGGL(kB_entry, dim3((BB * MM * 64 + 255) / 256), dim3(256),
                       0, stream, AB_arr, Mv0, entry, C);
  }
  const int ublocksD = (BB * C + 3) / 4;
  hipLaunchKernelGGL(kD_readout, dim3(ublocksD), dim3(256), 0, stream,
                     question, w_buf, e_buf, a_buf, entry, Mv0, k_emb,
                     f_W, f_b, p_W, p_b, out, logC, L, useChunks);
}

// Round 5
// 212.784 us; speedup vs baseline: 3.4632x; 1.3976x over previous
//
#include <hip/hip_runtime.h>
#include <cstddef>

// Problem constants (from reference)
#define QN 10000
#define DD 64
#define MM 50
#define BB 64
#define TT 512
#define WPAD 52   // padded w row stride in floats (208 B -> 16B-aligned rows)
#define MG 25     // m's per wave in the 2-way m-split scan kernels

// ===========================================================================
// kPre: one dispatch for all per-timestep precompute.
//   role w: w = softmax(k @ Mk^T)          (waves [0, NW/3))
//   role e: e = sigmoid(v@e_W+e_b) * mask  (waves [NW/3, 2NW/3))
//   role a: a = tanh(v@a_W+a_b) * mask     (waves [2NW/3, NW))
// Mask folded into e/a => downstream scan updates are branchless
// (mask!=1 -> e=a=0 -> alpha=1,beta=0 -> identity step).
// ===========================================================================
__global__ __launch_bounds__(256) void kPre(
    const int* __restrict__ question, const int* __restrict__ response,
    const float* __restrict__ mask,
    const float* __restrict__ k_emb, const float* __restrict__ v_emb,
    const float* __restrict__ Mk,
    const float* __restrict__ e_W, const float* __restrict__ e_b,
    const float* __restrict__ a_W, const float* __restrict__ a_b,
    float* __restrict__ w_buf, float* __restrict__ e_buf,
    float* __restrict__ a_buf) {
  const int lane = (int)(threadIdx.x & 63);
  const int wslot = __builtin_amdgcn_readfirstlane((int)(threadIdx.x >> 6));
  const int gw = blockIdx.x * 4 + wslot;
  const int NW = gridDim.x * 4;
  const int third = NW / 3;

  if (gw < third) {                       // ---- role: w (softmax)
    float mk[64];
    const int mrow = lane < MM ? lane : (MM - 1);
#pragma unroll
    for (int i = 0; i < 64; i += 4) {
      const float4 t4 = *(const float4*)(Mk + mrow * 64 + i);
      mk[i] = t4.x; mk[i + 1] = t4.y; mk[i + 2] = t4.z; mk[i + 3] = t4.w;
    }
    for (int row = gw; row < BB * TT; row += third) {
      const int q = question[row];                     // wave-uniform
      const float* __restrict__ krow = k_emb + (size_t)q * 64;
      float l0 = 0.f, l1 = 0.f, l2 = 0.f, l3 = 0.f;
#pragma unroll
      for (int i = 0; i < 64; i += 4) {
        const float4 kv = *(const float4*)(krow + i);  // uniform -> s_load
        l0 = fmaf(kv.x, mk[i], l0);
        l1 = fmaf(kv.y, mk[i + 1], l1);
        l2 = fmaf(kv.z, mk[i + 2], l2);
        l3 = fmaf(kv.w, mk[i + 3], l3);
      }
      const float lm = (l0 + l1) + (l2 + l3);
      float lv = (lane < MM) ? lm : -3.4e38f;
#pragma unroll
      for (int off = 32; off > 0; off >>= 1) lv = fmaxf(lv, __shfl_xor(lv, off));
      float pe = (lane < MM) ? __expf(lm - lv) : 0.f;
      float ss = pe;
#pragma unroll
      for (int off = 32; off > 0; off >>= 1) ss += __shfl_xor(ss, off);
      if (lane < MM) w_buf[(size_t)row * WPAD + lane] = pe / ss;
    }
  } else if (gw < 2 * third) {            // ---- role: e
    float ew[64];
#pragma unroll
    for (int i = 0; i < 64; ++i) ew[i] = e_W[i * 64 + lane];
    const float eb = e_b[lane];
    for (int row = gw - third; row < BB * TT; row += third) {
      const int q = question[row];
      const int r = response[row];
      const float mf = (mask[row] == 1.0f) ? 1.0f : 0.0f;
      const float* __restrict__ vrow = v_emb + ((size_t)q + (size_t)QN * r) * 64;
      float e0 = eb, e1 = 0.f;
#pragma unroll
      for (int i = 0; i < 64; i += 2) {
        const float2 vv = *(const float2*)(vrow + i);  // uniform -> s_load
        e0 = fmaf(vv.x, ew[i], e0);
        e1 = fmaf(vv.y, ew[i + 1], e1);
      }
      const float se = e0 + e1;
      e_buf[(size_t)row * 64 + lane] = mf / (1.f + __expf(-se));
    }
  } else {                                // ---- role: a
    const int stride = NW - 2 * third;
    float aw[64];
#pragma unroll
    for (int i = 0; i < 64; ++i) aw[i] = a_W[i * 64 + lane];
    const float ab = a_b[lane];
    for (int row = gw - 2 * third; row < BB * TT; row += stride) {
      const int q = question[row];
      const int r = response[row];
      const float mf = (mask[row] == 1.0f) ? 1.0f : 0.0f;
      const float* __restrict__ vrow = v_emb + ((size_t)q + (size_t)QN * r) * 64;
      float a0 = ab, a1 = 0.f;
#pragma unroll
      for (int i = 0; i < 64; i += 2) {
        const float2 vv = *(const float2*)(vrow + i);
        a0 = fmaf(vv.x, aw[i], a0);
        a1 = fmaf(vv.y, aw[i + 1], a1);
      }
      const float sa = a0 + a1;
      const float t2 = __expf(2.f * sa);
      a_buf[(size_t)row * 64 + lane] = mf * (1.f - 2.f / (t2 + 1.f));
    }
  }
}

// ===========================================================================
// kA: per-(b,chunk,mgroup) composed affine (A,B) per (m,d). One wave per
// unit2=(b*C+c)*2+g; lane=d; 25 m's in registers. Branchless inner loop.
//   AB layout: [b][c][m][d][{A,B}] (float2 per (m,d)) -> unit*6400 floats.
// ===========================================================================
__global__ __launch_bounds__(256) void kA_chunk(
    const float* __restrict__ w_buf, const float* __restrict__ e_buf,
    const float* __restrict__ a_buf, float* __restrict__ AB, int logC, int L) {
  const int lane = (int)(threadIdx.x & 63);
  const int wslot = __builtin_amdgcn_readfirstlane((int)(threadIdx.x >> 6));
  const int NW = gridDim.x * 4;
  const int C = 1 << logC;
  for (int u2 = blockIdx.x * 4 + wslot; u2 < BB * C * 2; u2 += NW) {
    const int g = u2 & 1;
    const int unit = u2 >> 1;                          // b*C + c
    const int b = unit >> logC;
    const int c = unit & (C - 1);
    float Am[MG], Bm[MG];
#pragma unroll
    for (int m = 0; m < MG; ++m) { Am[m] = 1.f; Bm[m] = 0.f; }
    const size_t rowbase = (size_t)b * TT + c * L;
#pragma unroll 2
    for (int j = 0; j < L; ++j) {
      const size_t row = rowbase + j;
      const float ed = e_buf[row * 64 + lane];
      const float ad = a_buf[row * 64 + lane];
      const float* __restrict__ wr = w_buf + row * WPAD + g * MG; // uniform
#pragma unroll
      for (int m = 0; m < MG; ++m) {
        const float wm = wr[m];
        const float al = fmaf(-wm, ed, 1.0f);
        const float be = wm * ad;
        Am[m] *= al;
        Bm[m] = fmaf(Bm[m], al, be);
      }
    }
    float* __restrict__ abp = AB + (size_t)unit * 6400 + (g * MG) * 128 + lane * 2;
#pragma unroll
    for (int m = 0; m < MG; ++m) {
      float2 o; o.x = Am[m]; o.y = Bm[m];
      *(float2*)(abp + m * 128) = o;
    }
  }
}

// ===========================================================================
// kB: sequential over C chunks, parallel over B*M*D = 204,800 elements.
// C==32 fast path: all 32 coefficient pairs loaded up front (one latency
// exposure). entry[c] = state before chunk c.
// ===========================================================================
__global__ __launch_bounds__(256) void kB_entry(
    const float* __restrict__ AB, const float* __restrict__ Mv0,
    float* __restrict__ entry, int C) {
  const int NT = gridDim.x * 256;
  for (int idx = blockIdx.x * 256 + (int)threadIdx.x; idx < BB * MM * 64;
       idx += NT) {
    const int b = idx / (MM * 64);
    const int r = idx - b * (MM * 64);                 // m*64 + d
    float s = Mv0[r];
    const float* __restrict__ abp = AB + (size_t)b * C * 6400 + (size_t)r * 2;
    float* __restrict__ ep = entry + (size_t)b * C * 3200 + r;
    if (C == 32) {
      float2 ab[32];
#pragma unroll
      for (int c = 0; c < 32; ++c)
        ab[c] = *(const float2*)(abp + (size_t)c * 6400);
#pragma unroll
      for (int c = 0; c < 32; ++c) {
        ep[(size_t)c * 3200] = s;
        s = fmaf(ab[c].x, s, ab[c].y);
      }
    } else {
      float2 cur = *(const float2*)(abp);
      for (int c = 0; c < C; ++c) {
        ep[(size_t)c * 3200] = s;
        float2 nxt; nxt.x = 1.f; nxt.y = 0.f;
        if (c + 1 < C) nxt = *(const float2*)(abp + (size_t)(c + 1) * 6400);
        s = fmaf(cur.x, s, cur.y);
        cur = nxt;
      }
    }
  }
}

// ===========================================================================
// kC: replay each chunk from its entry state, emitting partial reads.
// One wave per (b,c,mgroup); lane = d; s[25] in registers; w in SGPRs.
// Partial read sums (over this wave's 25 m's) go to read2[g]; k3 adds the
// two halves -- no cross-wave sync. Short per-step chain (1 store), so the
// 4096 waves pipeline loads across steps (round-1-proven; round-4's fused
// in-loop MLP was the 152us latency trap).
// ===========================================================================
__global__ __launch_bounds__(256) void kC_read(
    const float* __restrict__ w_buf, const float* __restrict__ e_buf,
    const float* __restrict__ a_buf, const float* __restrict__ entry,
    const float* __restrict__ Mv0, float* __restrict__ read2,
    int logC, int L, int use_mv0) {
  const int lane = (int)(threadIdx.x & 63);
  const int wslot = __builtin_amdgcn_readfirstlane((int)(threadIdx.x >> 6));
  const int NW = gridDim.x * 4;
  const int C = 1 << logC;
  const size_t RN = (size_t)BB * (TT - 1) * 64;
  for (int u2 = blockIdx.x * 4 + wslot; u2 < BB * C * 2; u2 += NW) {
    const int g = u2 & 1;
    const int unit = u2 >> 1;                          // b*C + c
    const int b = unit >> logC;
    const int c = unit & (C - 1);

    float s[MG];
    if (use_mv0) {
#pragma unroll
      for (int m = 0; m < MG; ++m) s[m] = Mv0[(g * MG + m) * 64 + lane];
    } else {
      const float* __restrict__ ep =
          entry + (size_t)unit * 3200 + (g * MG) * 64 + lane;
#pragma unroll
      for (int m = 0; m < MG; ++m) s[m] = ep[m * 64];
    }

    const int t0 = c * L;
    float* __restrict__ rb = read2 + (size_t)g * RN;
    int j0 = 0;
    if (t0 == 0) {
      // step t=0: update only, no read emitted
      const size_t row = (size_t)b * TT;
      const float ed = e_buf[row * 64 + lane];
      const float ad = a_buf[row * 64 + lane];
      const float* __restrict__ wr = w_buf + row * WPAD + g * MG;
#pragma unroll
      for (int m = 0; m < MG; ++m)
        s[m] = fmaf(wr[m], fmaf(-s[m], ed, ad), s[m]);
      j0 = 1;
    }
#pragma unroll 2
    for (int j = j0; j < L; ++j) {
      const int t = t0 + j;
      const size_t row = (size_t)b * TT + t;
      const float ed = e_buf[row * 64 + lane];
      const float ad = a_buf[row * 64 + lane];
      const float* __restrict__ wr = w_buf + row * WPAD + g * MG; // uniform
      float a0 = 0.f, a1 = 0.f;
#pragma unroll
      for (int m = 0; m < MG - 1; m += 2) {
        a0 = fmaf(wr[m], s[m], a0);
        a1 = fmaf(wr[m + 1], s[m + 1], a1);
      }
      a0 = fmaf(wr[MG - 1], s[MG - 1], a0);            // MG=25 is odd
      rb[((size_t)b * (TT - 1) + (t - 1)) * 64 + lane] = a0 + a1;
#pragma unroll
      for (int m = 0; m < MG; ++m)
        s[m] = fmaf(wr[m], fmaf(-s[m], ed, ad), s[m]);
    }
  }
}

// ===========================================================================
// k3: f = tanh([read | k_{t+1}] @ f_W + f_b); p = f @ p_W + p_b
// read = read2[part0] + read2[part1] (summed here for free). 4096 waves
// stream 32704 independent rows -- latency fully hidden by TLP.
// ===========================================================================
__global__ __launch_bounds__(256) void k3_out(
    const int* __restrict__ question, const float* __restrict__ k_emb,
    const float* __restrict__ read2,
    const float* __restrict__ f_W, const float* __restrict__ f_b,
    const float* __restrict__ p_W, const float* __restrict__ p_b,
    float* __restrict__ out) {
  const int lane = (int)(threadIdx.x & 63);
  const int wslot = __builtin_amdgcn_readfirstlane((int)(threadIdx.x >> 6));
  const int NW = gridDim.x * 4;
  const size_t RN = (size_t)BB * (TT - 1) * 64;

  float fw[128];
#pragma unroll
  for (int i = 0; i < 128; ++i) fw[i] = f_W[i * 64 + lane];
  const float fb = f_b[lane];
  const float pw = p_W[lane];
  const float pb = p_b[0];

  for (int row = blockIdx.x * 4 + wslot; row < BB * (TT - 1); row += NW) {
    const int b = row / (TT - 1);
    const int tp = row - b * (TT - 1);
    const float* __restrict__ r0 = read2 + (size_t)row * 64;
    const float* __restrict__ r1 = r0 + RN;
    const int qn = question[b * TT + tp + 1];          // wave-uniform
    const float* __restrict__ krow = k_emb + (size_t)qn * 64;

    float f0 = fb, f1 = 0.f, f2 = 0.f, f3 = 0.f;
#pragma unroll
    for (int i = 0; i < 64; i += 4) {
      const float4 x0 = *(const float4*)(r0 + i);
      const float4 x1 = *(const float4*)(r1 + i);
      f0 = fmaf(x0.x + x1.x, fw[i], f0);
      f1 = fmaf(x0.y + x1.y, fw[i + 1], f1);
      f2 = fmaf(x0.z + x1.z, fw[i + 2], f2);
      f3 = fmaf(x0.w + x1.w, fw[i + 3], f3);
    }
#pragma unroll
    for (int i = 0; i < 64; i += 4) {
      const float4 kv = *(const float4*)(krow + i);    // uniform -> s_load
      f0 = fmaf(kv.x, fw[64 + i], f0);
      f1 = fmaf(kv.y, fw[64 + i + 1], f1);
      f2 = fmaf(kv.z, fw[64 + i + 2], f2);
      f3 = fmaf(kv.w, fw[64 + i + 3], f3);
    }
    const float f = (f0 + f1) + (f2 + f3);
    const float t2 = __expf(2.f * f);
    const float fv = 1.f - 2.f / (t2 + 1.f);           // tanh
    float acc = fv * pw;
#pragma unroll
    for (int off = 32; off > 0; off >>= 1) acc += __shfl_xor(acc, off);
    if (lane == 0) out[row] = acc + pb;
  }
}

// ---------------------------------------------------------------------------
extern "C" void kernel_launch(void* const* d_in, const int* in_sizes, int n_in,
                              void* d_out, int out_size, void* d_ws, size_t ws_size,
                              hipStream_t stream) {
  const int*   question = (const int*)d_in[0];
  const int*   response = (const int*)d_in[1];
  const float* mask     = (const float*)d_in[2];
  const float* k_emb    = (const float*)d_in[3];
  const float* v_emb    = (const float*)d_in[4];
  const float* Mk       = (const float*)d_in[5];
  const float* Mv0      = (const float*)d_in[6];
  const float* e_W      = (const float*)d_in[7];
  const float* e_b      = (const float*)d_in[8];
  const float* a_W      = (const float*)d_in[9];
  const float* a_b      = (const float*)d_in[10];
  const float* f_W      = (const float*)d_in[11];
  const float* f_b      = (const float*)d_in[12];
  const float* p_W      = (const float*)d_in[13];
  const float* p_b      = (const float*)d_in[14];
  float* out = (float*)d_out;

  // workspace layout (floats)
  const size_t wN  = (size_t)BB * TT * WPAD;       // 1,703,936
  const size_t eN  = (size_t)BB * TT * 64;         // 2,097,152
  const size_t r2N = 2ull * BB * (TT - 1) * 64;    // 4,186,112
  float* ws = (float*)d_ws;
  float* w_buf  = ws;
  float* e_buf  = w_buf + wN;
  float* a_buf  = e_buf + eN;
  float* read2  = a_buf + eN;
  float* AB_arr = read2 + r2N;
  const size_t baseN = wN + 2 * eN + r2N;          // 10,084,352 floats

  // choose the largest chunk count C that fits the workspace
  // per-C cost: AB (6400*B*C) + entry (3200*B*C) floats
  int C = 32, logC = 5;
  while (C >= 2) {
    const size_t need = (baseN + 9600ull * BB * C) * sizeof(float);
    if (need <= ws_size) break;
    C >>= 1; logC -= 1;
  }
  int useChunks = (C >= 2);
  if (!useChunks) { C = 1; logC = 0; }
  const int L = TT / C;
  float* entry = AB_arr + 6400ull * BB * C;

  // 5 dispatches, no cooperative launch
  hipLaunchKernelGGL(kPre, dim3(2048), dim3(256), 0, stream,
                     question, response, mask, k_emb, v_emb, Mk,
                     e_W, e_b, a_W, a_b, w_buf, e_buf, a_buf);
  if (useChunks) {
    const int ublocksA = (BB * C * 2 + 3) / 4;
    hipLaunchKernelGGL(kA_chunk, dim3(ublocksA), dim3(256), 0, stream,
                       w_buf, e_buf, a_buf, AB_arr, logC, L);
    hipLaunchKernelGGL(kB_entry, dim3((BB * MM * 64 + 255) / 256), dim3(256),
                       0, stream, AB_arr, Mv0, entry, C);
  }
  const int ublocksC = (BB * C * 2 + 3) / 4;
  hipLaunchKernelGGL(kC_read, dim3(ublocksC), dim3(256), 0, stream,
                     w_buf, e_buf, a_buf, entry, Mv0, read2,
                     logC, L, useChunks ? 0 : 1);
  hipLaunchKernelGGL(k3_out, dim3(1024), dim3(256), 0, stream,
                     question, k_emb, read2, f_W, f_b, p_W, p_b, out);
}

// Round 6
// 211.425 us; speedup vs baseline: 3.4854x; 1.0064x over previous
//
#include <hip/hip_runtime.h>
#include <cstddef>

// Problem constants (from reference)
#define QN 10000
#define DD 64
#define MM 50
#define BB 64
#define TT 512
#define WPAD 52   // padded w row stride in floats (208 B -> 16B-aligned rows)
#define MG 25     // m's per wave in the 2-way m-split scan kernels

// ===========================================================================
// kPre: one dispatch for all per-timestep precompute, 4 ROWS PER WAVE batch
// so four independent embedding-gather chains are in flight (latency fix).
//   role 0: w = softmax(k @ Mk^T)
//   role 1: e = sigmoid(v@e_W+e_b) * mask
//   role 2: a = tanh(v@a_W+a_b) * mask
// Mask folded into e/a => downstream scan updates are branchless.
// ===========================================================================
__global__ __launch_bounds__(256) void kPre(
    const int* __restrict__ question, const int* __restrict__ response,
    const float* __restrict__ mask,
    const float* __restrict__ k_emb, const float* __restrict__ v_emb,
    const float* __restrict__ Mk,
    const float* __restrict__ e_W, const float* __restrict__ e_b,
    const float* __restrict__ a_W, const float* __restrict__ a_b,
    float* __restrict__ w_buf, float* __restrict__ e_buf,
    float* __restrict__ a_buf) {
  const int lane = (int)(threadIdx.x & 63);
  const int wslot = __builtin_amdgcn_readfirstlane((int)(threadIdx.x >> 6));
  const int gw = blockIdx.x * 4 + wslot;
  const int NW = gridDim.x * 4;
  const int third = NW / 3;
  if (gw >= 3 * third) return;
  const int role = gw / third;
  const int idx = gw - role * third;
  const int stride4 = third * 4;

  if (role == 0) {                        // ---- role: w (softmax), 4 rows/iter
    float mk[64];
    const int mrow = lane < MM ? lane : (MM - 1);
#pragma unroll
    for (int i = 0; i < 64; i += 4) {
      const float4 t4 = *(const float4*)(Mk + mrow * 64 + i);
      mk[i] = t4.x; mk[i + 1] = t4.y; mk[i + 2] = t4.z; mk[i + 3] = t4.w;
    }
    for (int base = idx * 4; base < BB * TT; base += stride4) {
      const int4 q4 = *(const int4*)(question + base);   // 4 indices, 1 load
      const float* __restrict__ kr0 = k_emb + (size_t)q4.x * 64;
      const float* __restrict__ kr1 = k_emb + (size_t)q4.y * 64;
      const float* __restrict__ kr2 = k_emb + (size_t)q4.z * 64;
      const float* __restrict__ kr3 = k_emb + (size_t)q4.w * 64;
      float l00=0.f,l01=0.f,l02=0.f,l03=0.f;   // row 0, 4-way split
      float l10=0.f,l11=0.f,l12=0.f,l13=0.f;   // row 1
      float l20=0.f,l21=0.f,l22=0.f,l23=0.f;   // row 2
      float l30=0.f,l31=0.f,l32=0.f,l33=0.f;   // row 3
#pragma unroll
      for (int i = 0; i < 64; i += 4) {
        const float4 k0 = *(const float4*)(kr0 + i);     // 4 independent
        const float4 k1 = *(const float4*)(kr1 + i);     // s_load chains
        const float4 k2 = *(const float4*)(kr2 + i);
        const float4 k3 = *(const float4*)(kr3 + i);
        l00 = fmaf(k0.x, mk[i], l00); l01 = fmaf(k0.y, mk[i+1], l01);
        l02 = fmaf(k0.z, mk[i+2], l02); l03 = fmaf(k0.w, mk[i+3], l03);
        l10 = fmaf(k1.x, mk[i], l10); l11 = fmaf(k1.y, mk[i+1], l11);
        l12 = fmaf(k1.z, mk[i+2], l12); l13 = fmaf(k1.w, mk[i+3], l13);
        l20 = fmaf(k2.x, mk[i], l20); l21 = fmaf(k2.y, mk[i+1], l21);
        l22 = fmaf(k2.z, mk[i+2], l22); l23 = fmaf(k2.w, mk[i+3], l23);
        l30 = fmaf(k3.x, mk[i], l30); l31 = fmaf(k3.y, mk[i+1], l31);
        l32 = fmaf(k3.z, mk[i+2], l32); l33 = fmaf(k3.w, mk[i+3], l33);
      }
      float lm[4];
      lm[0] = (l00 + l01) + (l02 + l03);
      lm[1] = (l10 + l11) + (l12 + l13);
      lm[2] = (l20 + l21) + (l22 + l23);
      lm[3] = (l30 + l31) + (l32 + l33);
#pragma unroll
      for (int r = 0; r < 4; ++r) {
        float lv = (lane < MM) ? lm[r] : -3.4e38f;
#pragma unroll
        for (int off = 32; off > 0; off >>= 1) lv = fmaxf(lv, __shfl_xor(lv, off));
        float pe = (lane < MM) ? __expf(lm[r] - lv) : 0.f;
        float ss = pe;
#pragma unroll
        for (int off = 32; off > 0; off >>= 1) ss += __shfl_xor(ss, off);
        if (lane < MM) w_buf[(size_t)(base + r) * WPAD + lane] = pe / ss;
      }
    }
  } else if (role == 1) {                 // ---- role: e, 4 rows/iter
    float ew[64];
#pragma unroll
    for (int i = 0; i < 64; ++i) ew[i] = e_W[i * 64 + lane];
    const float eb = e_b[lane];
    for (int base = idx * 4; base < BB * TT; base += stride4) {
      const int4 q4 = *(const int4*)(question + base);
      const int4 r4 = *(const int4*)(response + base);
      const float4 m4 = *(const float4*)(mask + base);
      const float* __restrict__ v0 = v_emb + ((size_t)q4.x + (size_t)QN * r4.x) * 64;
      const float* __restrict__ v1 = v_emb + ((size_t)q4.y + (size_t)QN * r4.y) * 64;
      const float* __restrict__ v2 = v_emb + ((size_t)q4.z + (size_t)QN * r4.z) * 64;
      const float* __restrict__ v3 = v_emb + ((size_t)q4.w + (size_t)QN * r4.w) * 64;
      float e00 = eb, e01 = 0.f, e10 = eb, e11 = 0.f;
      float e20 = eb, e21 = 0.f, e30 = eb, e31 = 0.f;
#pragma unroll
      for (int i = 0; i < 64; i += 2) {
        const float2 a0 = *(const float2*)(v0 + i);      // 4 independent
        const float2 a1 = *(const float2*)(v1 + i);      // s_load chains
        const float2 a2 = *(const float2*)(v2 + i);
        const float2 a3 = *(const float2*)(v3 + i);
        e00 = fmaf(a0.x, ew[i], e00); e01 = fmaf(a0.y, ew[i+1], e01);
        e10 = fmaf(a1.x, ew[i], e10); e11 = fmaf(a1.y, ew[i+1], e11);
        e20 = fmaf(a2.x, ew[i], e20); e21 = fmaf(a2.y, ew[i+1], e21);
        e30 = fmaf(a3.x, ew[i], e30); e31 = fmaf(a3.y, ew[i+1], e31);
      }
      const float mf0 = (m4.x == 1.0f) ? 1.0f : 0.0f;
      const float mf1 = (m4.y == 1.0f) ? 1.0f : 0.0f;
      const float mf2 = (m4.z == 1.0f) ? 1.0f : 0.0f;
      const float mf3 = (m4.w == 1.0f) ? 1.0f : 0.0f;
      e_buf[(size_t)(base + 0) * 64 + lane] = mf0 / (1.f + __expf(-(e00 + e01)));
      e_buf[(size_t)(base + 1) * 64 + lane] = mf1 / (1.f + __expf(-(e10 + e11)));
      e_buf[(size_t)(base + 2) * 64 + lane] = mf2 / (1.f + __expf(-(e20 + e21)));
      e_buf[(size_t)(base + 3) * 64 + lane] = mf3 / (1.f + __expf(-(e30 + e31)));
    }
  } else {                                // ---- role: a, 4 rows/iter
    float aw[64];
#pragma unroll
    for (int i = 0; i < 64; ++i) aw[i] = a_W[i * 64 + lane];
    const float ab = a_b[lane];
    for (int base = idx * 4; base < BB * TT; base += stride4) {
      const int4 q4 = *(const int4*)(question + base);
      const int4 r4 = *(const int4*)(response + base);
      const float4 m4 = *(const float4*)(mask + base);
      const float* __restrict__ v0 = v_emb + ((size_t)q4.x + (size_t)QN * r4.x) * 64;
      const float* __restrict__ v1 = v_emb + ((size_t)q4.y + (size_t)QN * r4.y) * 64;
      const float* __restrict__ v2 = v_emb + ((size_t)q4.z + (size_t)QN * r4.z) * 64;
      const float* __restrict__ v3 = v_emb + ((size_t)q4.w + (size_t)QN * r4.w) * 64;
      float a00 = ab, a01 = 0.f, a10 = ab, a11 = 0.f;
      float a20 = ab, a21 = 0.f, a30 = ab, a31 = 0.f;
#pragma unroll
      for (int i = 0; i < 64; i += 2) {
        const float2 x0 = *(const float2*)(v0 + i);
        const float2 x1 = *(const float2*)(v1 + i);
        const float2 x2 = *(const float2*)(v2 + i);
        const float2 x3 = *(const float2*)(v3 + i);
        a00 = fmaf(x0.x, aw[i], a00); a01 = fmaf(x0.y, aw[i+1], a01);
        a10 = fmaf(x1.x, aw[i], a10); a11 = fmaf(x1.y, aw[i+1], a11);
        a20 = fmaf(x2.x, aw[i], a20); a21 = fmaf(x2.y, aw[i+1], a21);
        a30 = fmaf(x3.x, aw[i], a30); a31 = fmaf(x3.y, aw[i+1], a31);
      }
      const float mf0 = (m4.x == 1.0f) ? 1.0f : 0.0f;
      const float mf1 = (m4.y == 1.0f) ? 1.0f : 0.0f;
      const float mf2 = (m4.z == 1.0f) ? 1.0f : 0.0f;
      const float mf3 = (m4.w == 1.0f) ? 1.0f : 0.0f;
      const float s0 = a00 + a01, s1 = a10 + a11, s2 = a20 + a21, s3 = a30 + a31;
      a_buf[(size_t)(base + 0) * 64 + lane] = mf0 * (1.f - 2.f / (__expf(2.f * s0) + 1.f));
      a_buf[(size_t)(base + 1) * 64 + lane] = mf1 * (1.f - 2.f / (__expf(2.f * s1) + 1.f));
      a_buf[(size_t)(base + 2) * 64 + lane] = mf2 * (1.f - 2.f / (__expf(2.f * s2) + 1.f));
      a_buf[(size_t)(base + 3) * 64 + lane] = mf3 * (1.f - 2.f / (__expf(2.f * s3) + 1.f));
    }
  }
}

// ===========================================================================
// kA16: C=32 specialized compose (L=16, FULLY unrolled). All 16 e's and 16
// a's prefetched into registers first (32 independent loads, ONE latency
// exposure) — the round-5 unroll-2 version exposed ~8 serial latencies.
// Full unroll keeps ev[j]/av[j] statically indexed (registers, not scratch).
// ===========================================================================
__global__ __launch_bounds__(256) void kA16(
    const float* __restrict__ w_buf, const float* __restrict__ e_buf,
    const float* __restrict__ a_buf, float* __restrict__ AB) {
  const int lane = (int)(threadIdx.x & 63);
  const int wslot = __builtin_amdgcn_readfirstlane((int)(threadIdx.x >> 6));
  const int u2 = blockIdx.x * 4 + wslot;
  if (u2 >= BB * 32 * 2) return;
  const int g = u2 & 1;
  const int unit = u2 >> 1;                            // b*32 + c
  const int b = unit >> 5;
  const int c = unit & 31;
  const size_t rowbase = (size_t)b * TT + c * 16;
  const size_t eb0 = rowbase * 64 + lane;

  float ev[16], av[16];
#pragma unroll
  for (int j = 0; j < 16; ++j) {
    ev[j] = e_buf[eb0 + (size_t)j * 64];
    av[j] = a_buf[eb0 + (size_t)j * 64];
  }

  float Am[MG], Bm[MG];
#pragma unroll
  for (int m = 0; m < MG; ++m) { Am[m] = 1.f; Bm[m] = 0.f; }

#pragma unroll
  for (int j = 0; j < 16; ++j) {
    const float* __restrict__ wr = w_buf + (rowbase + j) * WPAD + g * MG;
#pragma unroll
    for (int m = 0; m < MG; ++m) {
      const float wm = wr[m];
      const float al = fmaf(-wm, ev[j], 1.0f);
      const float be = wm * av[j];
      Am[m] *= al;
      Bm[m] = fmaf(Bm[m], al, be);
    }
  }
  float* __restrict__ abp = AB + (size_t)unit * 6400 + (g * MG) * 128 + lane * 2;
#pragma unroll
  for (int m = 0; m < MG; ++m) {
    float2 o; o.x = Am[m]; o.y = Bm[m];
    *(float2*)(abp + m * 128) = o;
  }
}

// ===========================================================================
// kB: sequential over C chunks, parallel over B*M*D = 204,800 elements.
// C==32 fast path: all 32 coefficient pairs loaded up front.
// ===========================================================================
__global__ __launch_bounds__(256) void kB_entry(
    const float* __restrict__ AB, const float* __restrict__ Mv0,
    float* __restrict__ entry, int C) {
  const int NT = gridDim.x * 256;
  for (int idx = blockIdx.x * 256 + (int)threadIdx.x; idx < BB * MM * 64;
       idx += NT) {
    const int b = idx / (MM * 64);
    const int r = idx - b * (MM * 64);                 // m*64 + d
    float s = Mv0[r];
    const float* __restrict__ abp = AB + (size_t)b * C * 6400 + (size_t)r * 2;
    float* __restrict__ ep = entry + (size_t)b * C * 3200 + r;
    if (C == 32) {
      float2 ab[32];
#pragma unroll
      for (int c = 0; c < 32; ++c)
        ab[c] = *(const float2*)(abp + (size_t)c * 6400);
#pragma unroll
      for (int c = 0; c < 32; ++c) {
        ep[(size_t)c * 3200] = s;
        s = fmaf(ab[c].x, s, ab[c].y);
      }
    } else {
      float2 cur = *(const float2*)(abp);
      for (int c = 0; c < C; ++c) {
        ep[(size_t)c * 3200] = s;
        float2 nxt; nxt.x = 1.f; nxt.y = 0.f;
        if (c + 1 < C) nxt = *(const float2*)(abp + (size_t)(c + 1) * 6400);
        s = fmaf(cur.x, s, cur.y);
        cur = nxt;
      }
    }
  }
}

// ===========================================================================
// kC16: C=32 specialized replay (L=16, FULLY unrolled), same prefetch-all
// ev/av scheme as kA16; entry s[25] loads are independent and batched.
// Per step: partial read dot (this wave's 25 m's) -> read2[g], then
// branchless update. t>=1 guard only fires false for (c==0, j==0).
// ===========================================================================
__global__ __launch_bounds__(256) void kC16(
    const float* __restrict__ w_buf, const float* __restrict__ e_buf,
    const float* __restrict__ a_buf, const float* __restrict__ entry,
    float* __restrict__ read2) {
  const int lane = (int)(threadIdx.x & 63);
  const int wslot = __builtin_amdgcn_readfirstlane((int)(threadIdx.x >> 6));
  const int u2 = blockIdx.x * 4 + wslot;
  if (u2 >= BB * 32 * 2) return;
  const int g = u2 & 1;
  const int unit = u2 >> 1;                            // b*32 + c
  const int b = unit >> 5;
  const int c = unit & 31;
  const size_t RN = (size_t)BB * (TT - 1) * 64;
  const size_t rowbase = (size_t)b * TT + c * 16;
  const size_t eb0 = rowbase * 64 + lane;

  float ev[16], av[16];
#pragma unroll
  for (int j = 0; j < 16; ++j) {
    ev[j] = e_buf[eb0 + (size_t)j * 64];
    av[j] = a_buf[eb0 + (size_t)j * 64];
  }

  float s[MG];
  {
    const float* __restrict__ ep =
        entry + (size_t)unit * 3200 + (g * MG) * 64 + lane;
#pragma unroll
    for (int m = 0; m < MG; ++m) s[m] = ep[m * 64];    // 25 independent loads
  }

  const int t0 = c * 16;
  float* __restrict__ rb = read2 + (size_t)g * RN;
#pragma unroll
  for (int j = 0; j < 16; ++j) {
    const int t = t0 + j;
    const float* __restrict__ wr = w_buf + (rowbase + j) * WPAD + g * MG;
    if (t >= 1) {                                      // false only c==0,j==0
      float a0 = 0.f, a1 = 0.f;
#pragma unroll
      for (int m = 0; m < MG - 1; m += 2) {
        a0 = fmaf(wr[m], s[m], a0);
        a1 = fmaf(wr[m + 1], s[m + 1], a1);
      }
      a0 = fmaf(wr[MG - 1], s[MG - 1], a0);            // MG=25 is odd
      rb[((size_t)b * (TT - 1) + (t - 1)) * 64 + lane] = a0 + a1;
    }
#pragma unroll
    for (int m = 0; m < MG; ++m)
      s[m] = fmaf(wr[m], fmaf(-s[m], ev[j], av[j]), s[m]);
  }
}

// ===========================================================================
// Generic fallback scan kernels (used only if C != 32).
// ===========================================================================
__global__ __launch_bounds__(256) void kA_chunk(
    const float* __restrict__ w_buf, const float* __restrict__ e_buf,
    const float* __restrict__ a_buf, float* __restrict__ AB, int logC, int L) {
  const int lane = (int)(threadIdx.x & 63);
  const int wslot = __builtin_amdgcn_readfirstlane((int)(threadIdx.x >> 6));
  const int NW = gridDim.x * 4;
  const int C = 1 << logC;
  for (int u2 = blockIdx.x * 4 + wslot; u2 < BB * C * 2; u2 += NW) {
    const int g = u2 & 1;
    const int unit = u2 >> 1;
    const int b = unit >> logC;
    const int c = unit & (C - 1);
    float Am[MG], Bm[MG];
#pragma unroll
    for (int m = 0; m < MG; ++m) { Am[m] = 1.f; Bm[m] = 0.f; }
    const size_t rowbase = (size_t)b * TT + c * L;
#pragma unroll 2
    for (int j = 0; j < L; ++j) {
      const size_t row = rowbase + j;
      const float ed = e_buf[row * 64 + lane];
      const float ad = a_buf[row * 64 + lane];
      const float* __restrict__ wr = w_buf + row * WPAD + g * MG;
#pragma unroll
      for (int m = 0; m < MG; ++m) {
        const float wm = wr[m];
        const float al = fmaf(-wm, ed, 1.0f);
        const float be = wm * ad;
        Am[m] *= al;
        Bm[m] = fmaf(Bm[m], al, be);
      }
    }
    float* __restrict__ abp = AB + (size_t)unit * 6400 + (g * MG) * 128 + lane * 2;
#pragma unroll
    for (int m = 0; m < MG; ++m) {
      float2 o; o.x = Am[m]; o.y = Bm[m];
      *(float2*)(abp + m * 128) = o;
    }
  }
}

__global__ __launch_bounds__(256) void kC_read(
    const float* __restrict__ w_buf, const float* __restrict__ e_buf,
    const float* __restrict__ a_buf, const float* __restrict__ entry,
    const float* __restrict__ Mv0, float* __restrict__ read2,
    int logC, int L, int use_mv0) {
  const int lane = (int)(threadIdx.x & 63);
  const int wslot = __builtin_amdgcn_readfirstlane((int)(threadIdx.x >> 6));
  const int NW = gridDim.x * 4;
  const int C = 1 << logC;
  const size_t RN = (size_t)BB * (TT - 1) * 64;
  for (int u2 = blockIdx.x * 4 + wslot; u2 < BB * C * 2; u2 += NW) {
    const int g = u2 & 1;
    const int unit = u2 >> 1;
    const int b = unit >> logC;
    const int c = unit & (C - 1);
    float s[MG];
    if (use_mv0) {
#pragma unroll
      for (int m = 0; m < MG; ++m) s[m] = Mv0[(g * MG + m) * 64 + lane];
    } else {
      const float* __restrict__ ep =
          entry + (size_t)unit * 3200 + (g * MG) * 64 + lane;
#pragma unroll
      for (int m = 0; m < MG; ++m) s[m] = ep[m * 64];
    }
    const int t0 = c * L;
    float* __restrict__ rb = read2 + (size_t)g * RN;
    for (int j = 0; j < L; ++j) {
      const int t = t0 + j;
      const size_t row = (size_t)b * TT + t;
      const float ed = e_buf[row * 64 + lane];
      const float ad = a_buf[row * 64 + lane];
      const float* __restrict__ wr = w_buf + row * WPAD + g * MG;
      if (t >= 1) {
        float a0 = 0.f, a1 = 0.f;
#pragma unroll
        for (int m = 0; m < MG - 1; m += 2) {
          a0 = fmaf(wr[m], s[m], a0);
          a1 = fmaf(wr[m + 1], s[m + 1], a1);
        }
        a0 = fmaf(wr[MG - 1], s[MG - 1], a0);
        rb[((size_t)b * (TT - 1) + (t - 1)) * 64 + lane] = a0 + a1;
      }
#pragma unroll
      for (int m = 0; m < MG; ++m)
        s[m] = fmaf(wr[m], fmaf(-s[m], ed, ad), s[m]);
    }
  }
}

// ===========================================================================
// k3: f = tanh([read | k_{t+1}] @ f_W + f_b); p = f @ p_W + p_b
// read = read2[part0] + read2[part1]. 4096 waves stream 32704 rows.
// ===========================================================================
__global__ __launch_bounds__(256) void k3_out(
    const int* __restrict__ question, const float* __restrict__ k_emb,
    const float* __restrict__ read2,
    const float* __restrict__ f_W, const float* __restrict__ f_b,
    const float* __restrict__ p_W, const float* __restrict__ p_b,
    float* __restrict__ out) {
  const int lane = (int)(threadIdx.x & 63);
  const int wslot = __builtin_amdgcn_readfirstlane((int)(threadIdx.x >> 6));
  const int NW = gridDim.x * 4;
  const size_t RN = (size_t)BB * (TT - 1) * 64;

  float fw[128];
#pragma unroll
  for (int i = 0; i < 128; ++i) fw[i] = f_W[i * 64 + lane];
  const float fb = f_b[lane];
  const float pw = p_W[lane];
  const float pb = p_b[0];

  for (int row = blockIdx.x * 4 + wslot; row < BB * (TT - 1); row += NW) {
    const int b = row / (TT - 1);
    const int tp = row - b * (TT - 1);
    const float* __restrict__ r0 = read2 + (size_t)row * 64;
    const float* __restrict__ r1 = r0 + RN;
    const int qn = question[b * TT + tp + 1];          // wave-uniform
    const float* __restrict__ krow = k_emb + (size_t)qn * 64;

    float f0 = fb, f1 = 0.f, f2 = 0.f, f3 = 0.f;
#pragma unroll
    for (int i = 0; i < 64; i += 4) {
      const float4 x0 = *(const float4*)(r0 + i);
      const float4 x1 = *(const float4*)(r1 + i);
      f0 = fmaf(x0.x + x1.x, fw[i], f0);
      f1 = fmaf(x0.y + x1.y, fw[i + 1], f1);
      f2 = fmaf(x0.z + x1.z, fw[i + 2], f2);
      f3 = fmaf(x0.w + x1.w, fw[i + 3], f3);
    }
#pragma unroll
    for (int i = 0; i < 64; i += 4) {
      const float4 kv = *(const float4*)(krow + i);    // uniform -> s_load
      f0 = fmaf(kv.x, fw[64 + i], f0);
      f1 = fmaf(kv.y, fw[64 + i + 1], f1);
      f2 = fmaf(kv.z, fw[64 + i + 2], f2);
      f3 = fmaf(kv.w, fw[64 + i + 3], f3);
    }
    const float f = (f0 + f1) + (f2 + f3);
    const float t2 = __expf(2.f * f);
    const float fv = 1.f - 2.f / (t2 + 1.f);           // tanh
    float acc = fv * pw;
#pragma unroll
    for (int off = 32; off > 0; off >>= 1) acc += __shfl_xor(acc, off);
    if (lane == 0) out[row] = acc + pb;
  }
}

// ---------------------------------------------------------------------------
extern "C" void kernel_launch(void* const* d_in, const int* in_sizes, int n_in,
                              void* d_out, int out_size, void* d_ws, size_t ws_size,
                              hipStream_t stream) {
  const int*   question = (const int*)d_in[0];
  const int*   response = (const int*)d_in[1];
  const float* mask     = (const float*)d_in[2];
  const float* k_emb    = (const float*)d_in[3];
  const float* v_emb    = (const float*)d_in[4];
  const float* Mk       = (const float*)d_in[5];
  const float* Mv0      = (const float*)d_in[6];
  const float* e_W      = (const float*)d_in[7];
  const float* e_b      = (const float*)d_in[8];
  const float* a_W      = (const float*)d_in[9];
  const float* a_b      = (const float*)d_in[10];
  const float* f_W      = (const float*)d_in[11];
  const float* f_b      = (const float*)d_in[12];
  const float* p_W      = (const float*)d_in[13];
  const float* p_b      = (const float*)d_in[14];
  float* out = (float*)d_out;

  // workspace layout (floats)
  const size_t wN  = (size_t)BB * TT * WPAD;       // 1,703,936
  const size_t eN  = (size_t)BB * TT * 64;         // 2,097,152
  const size_t r2N = 2ull * BB * (TT - 1) * 64;    // 4,186,112
  float* ws = (float*)d_ws;
  float* w_buf  = ws;
  float* e_buf  = w_buf + wN;
  float* a_buf  = e_buf + eN;
  float* read2  = a_buf + eN;
  float* AB_arr = read2 + r2N;
  const size_t baseN = wN + 2 * eN + r2N;          // 10,084,352 floats

  // choose the largest chunk count C that fits the workspace
  int C = 32, logC = 5;
  while (C >= 2) {
    const size_t need = (baseN + 9600ull * BB * C) * sizeof(float);
    if (need <= ws_size) break;
    C >>= 1; logC -= 1;
  }
  int useChunks = (C >= 2);
  if (!useChunks) { C = 1; logC = 0; }
  const int L = TT / C;
  float* entry = AB_arr + 6400ull * BB * C;

  hipLaunchKernelGGL(kPre, dim3(2048), dim3(256), 0, stream,
                     question, response, mask, k_emb, v_emb, Mk,
                     e_W, e_b, a_W, a_b, w_buf, e_buf, a_buf);

  if (C == 32) {
    hipLaunchKernelGGL(kA16, dim3(1024), dim3(256), 0, stream,
                       w_buf, e_buf, a_buf, AB_arr);
    hipLaunchKernelGGL(kB_entry, dim3((BB * MM * 64 + 255) / 256), dim3(256),
                       0, stream, AB_arr, Mv0, entry, C);
    hipLaunchKernelGGL(kC16, dim3(1024), dim3(256), 0, stream,
                       w_buf, e_buf, a_buf, entry, read2);
  } else {
    if (useChunks) {
      const int ublocksA = (BB * C * 2 + 3) / 4;
      hipLaunchKernelGGL(kA_chunk, dim3(ublocksA), dim3(256), 0, stream,
                         w_buf, e_buf, a_buf, AB_arr, logC, L);
      hipLaunchKernelGGL(kB_entry, dim3((BB * MM * 64 + 255) / 256), dim3(256),
                         0, stream, AB_arr, Mv0, entry, C);
    }
    const int ublocksC = (BB * C * 2 + 3) / 4;
    hipLaunchKernelGGL(kC_read, dim3(ublocksC), dim3(256), 0, stream,
                       w_buf, e_buf, a_buf, entry, Mv0, read2,
                       logC, L, useChunks ? 0 : 1);
  }

  hipLaunchKernelGGL(k3_out, dim3(1024), dim3(256), 0, stream,
                     question, k_emb, read2, f_W, f_b, p_W, p_b, out);
}